// Round 5
// baseline (831.782 us; speedup 1.0000x reference)
//
#include <hip/hip_runtime.h>

#define NTOK 8192
#define CDIM 1024
#define ENUM 8
#define HDIM 4096

typedef unsigned short u16;
typedef unsigned int u32;
typedef __attribute__((ext_vector_type(8))) short s16x8;
typedef __attribute__((ext_vector_type(4))) float f32x4;

static __device__ __forceinline__ u16 f2bf(float f) {
  union { float f; u32 u; } v; v.f = f;
  u32 r = v.u + 0x7fffu + ((v.u >> 16) & 1u);
  return (u16)(r >> 16);
}
static __device__ __forceinline__ u32 pack2(float a, float b) {
  return (u32)f2bf(a) | ((u32)f2bf(b) << 16);
}
static __device__ __forceinline__ float bflo(u32 v) {
  union { u32 u; float f; } x; x.u = v << 16; return x.f;
}
static __device__ __forceinline__ float bfhi(u32 v) {
  union { u32 u; float f; } x; x.u = v & 0xffff0000u; return x.f;
}

typedef __attribute__((address_space(1))) const void gvoid;
typedef __attribute__((address_space(3))) void lvoid;
static __device__ __forceinline__ void gload16(const u16* g, u16* l) {
  __builtin_amdgcn_global_load_lds((gvoid*)g, (lvoid*)l, 16, 0, 0);
}

static __device__ __forceinline__ float gelu_fast(float v) {
  float u = v * (1.5957691216f + 0.1426929792f * v * v);
  return v / (1.f + __expf(-u));
}

// ---------------- weight convert + transpose: w[E][K][N] f32 -> wt[E][N][K] bf16 ----
__global__ void wconv_kernel(const float* __restrict__ w, u16* __restrict__ wt,
                             int K, int N) {
  __shared__ float lt[64][65];
  const int e = blockIdx.z, k0 = blockIdx.y * 64, n0 = blockIdx.x * 64;
  const float* src = w + (size_t)e * K * N;
  u16* dst = wt + (size_t)e * N * K;
  const int t = threadIdx.x;
  const int tr = t >> 4, tc = (t & 15) * 4;
#pragma unroll
  for (int i = 0; i < 4; ++i) {
    float4 v = *(const float4*)(src + (size_t)(k0 + tr + i * 16) * N + n0 + tc);
    lt[tr + i * 16][tc] = v.x; lt[tr + i * 16][tc + 1] = v.y;
    lt[tr + i * 16][tc + 2] = v.z; lt[tr + i * 16][tc + 3] = v.w;
  }
  __syncthreads();
#pragma unroll
  for (int i = 0; i < 4; ++i) {
    int n = tr + i * 16;
    uint2 o;
    o.x = pack2(lt[tc + 0][n], lt[tc + 1][n]);
    o.y = pack2(lt[tc + 2][n], lt[tc + 3][n]);
    *(uint2*)(dst + (size_t)(n0 + n) * K + k0 + tc) = o;
  }
}

// ---------------- gating ----------------
__global__ void gate_kernel(const float* __restrict__ x, const float* __restrict__ wg,
                            int* __restrict__ cnt, int* __restrict__ tok_e,
                            float* __restrict__ tok_w) {
  int gw = (blockIdx.x * blockDim.x + threadIdx.x) >> 6;
  int lane = threadIdx.x & 63;
  if (gw >= NTOK) return;
  const float* xr = x + (size_t)gw * CDIM;
  float acc[ENUM];
#pragma unroll
  for (int e = 0; e < ENUM; ++e) acc[e] = 0.f;
  for (int i = 0; i < CDIM / 64; ++i) {
    int c = i * 64 + lane;
    float xv = xr[c];
    float4 wa = *(const float4*)(wg + (size_t)c * ENUM);
    float4 wb = *(const float4*)(wg + (size_t)c * ENUM + 4);
    acc[0] += xv * wa.x; acc[1] += xv * wa.y; acc[2] += xv * wa.z; acc[3] += xv * wa.w;
    acc[4] += xv * wb.x; acc[5] += xv * wb.y; acc[6] += xv * wb.z; acc[7] += xv * wb.w;
  }
#pragma unroll
  for (int e = 0; e < ENUM; ++e) {
#pragma unroll
    for (int off = 32; off > 0; off >>= 1) acc[e] += __shfl_xor(acc[e], off);
  }
  if (lane == 0) {
    int i0 = 0; float v0 = acc[0];
#pragma unroll
    for (int e = 1; e < ENUM; ++e) if (acc[e] > v0) { v0 = acc[e]; i0 = e; }
    int i1 = -1; float v1 = -3.4e38f;
#pragma unroll
    for (int e = 0; e < ENUM; ++e) if (e != i0 && acc[e] > v1) { v1 = acc[e]; i1 = e; }
    float ex = expf(v1 - v0);
    float den = 1.f + ex;
    tok_e[gw * 2] = i0;     tok_w[gw * 2] = 1.f / den;
    tok_e[gw * 2 + 1] = i1; tok_w[gw * 2 + 1] = ex / den;
    atomicAdd(&cnt[i0], 1); atomicAdd(&cnt[i1], 1);
  }
}

__global__ void offsets_kernel(const int* __restrict__ cnt, int* __restrict__ offs) {
  if (threadIdx.x == 0 && blockIdx.x == 0) {
    int s = 0;
    for (int e = 0; e < ENUM; ++e) { offs[e] = s; s += cnt[e]; }
  }
}

__global__ void assign_kernel(const int* __restrict__ tok_e, const int* __restrict__ offs,
                              int* __restrict__ fill, int* __restrict__ slot_tok,
                              int* __restrict__ tok_slot) {
  int n = blockIdx.x * blockDim.x + threadIdx.x;
  if (n >= NTOK) return;
#pragma unroll
  for (int j = 0; j < 2; ++j) {
    int e = tok_e[n * 2 + j];
    int pos = atomicAdd(&fill[e], 1);
    int slot = offs[e] + pos;
    slot_tok[slot] = n;
    tok_slot[n * 2 + j] = slot;
  }
}

__global__ void gather_kernel(const float* __restrict__ x, const int* __restrict__ slot_tok,
                              u16* __restrict__ xg) {
  int gid = blockIdx.x * blockDim.x + threadIdx.x;
  int slot = gid >> 8;
  int c4 = (gid & 255) * 4;
  int tok = slot_tok[slot];
  float4 v = *(const float4*)(x + (size_t)tok * CDIM + c4);
  uint2 o; o.x = pack2(v.x, v.y); o.y = pack2(v.z, v.w);
  *(uint2*)(xg + (size_t)slot * CDIM + c4) = o;
}

// ---------------- expert GEMMs: 256x256, BK=64, fine-phase m201-style schedule ----
// 8 waves (2M x 4N), per-wave 128x64 out. K-tile split into 4 half-tiles of 16 KB:
// {A k-half0, B k-half0, A k-half1, B k-half1}, double-buffered (128 KB LDS).
// Per phase: {<=10 ds_read_b128, stage 1 half-tile (2 gload_lds), barrier,
//             lgkmcnt(0)+sched_barrier, setprio(1), 16 MFMA, setprio(0),
//             vmcnt(4), barrier}.
// Hazards: half staged at phase q is first read at q+3 or later; per-phase
// vmcnt(4)+barrier guarantees all stages <= q-2 retired CU-wide. Write-after-read:
// stages go to dbuf d^1 whose previous contents were last read one K-tile ago.
template <int PHASE, int KK, int NN, int NTI>
__global__ __launch_bounds__(512, 2) void moe_gemm(
    const u16* __restrict__ Ag, const u16* __restrict__ Bt, const float* __restrict__ bias,
    u16* __restrict__ outp,
    const int* __restrict__ cnts, const int* __restrict__ offs) {
  const int per_e = 64 * NTI;
  const int e = blockIdx.x / per_e;
  const int r = blockIdx.x % per_e;
  int mt, nt;
  if (r < 8 * NTI) {
    const int chunk = r & 7, inner = r >> 3;
    if (NTI == 16) {
      mt = ((chunk >> 2) << 2) | (inner >> 2);
      nt = ((chunk & 3) << 2) | (inner & 3);
    } else {
      mt = ((chunk >> 1) << 1) | (inner >> 1);
      nt = ((chunk & 1) << 1) | (inner & 1);
    }
  } else {
    const int rr = r - 8 * NTI;
    mt = 8 + rr / NTI;
    nt = rr % NTI;
  }
  const int cnt = cnts[e];
  if (mt * 256 >= cnt) return;
  const int moff = offs[e];

  const int tid = threadIdx.x;
  const int wv = tid >> 6, ln = tid & 63;
  const int lr = ln & 15, lg = ln >> 4;
  const int wm = wv >> 2, wn = wv & 3;

  __shared__ __align__(16) u16 lds[2][4][8192];  // [dbuf][Ak0,Bk0,Ak1,Bk1] = 128 KB

  const u16* Abase = Ag + (size_t)moff * KK;
  const u16* Bbase = Bt + (size_t)e * NN * KK + (size_t)nt * 256 * KK;

  // staging geometry: 1024 16B-octets per half-tile; octet idx = tid (+512)
  // row = idx>>2 (64B rows of 32 k-elems), dest oct = idx&3,
  // source logical oct = dest ^ (row&3)  (both-sides swizzle, rule #21)
  const int srow = tid >> 2;
  const int slo = (tid & 3) ^ (srow & 3);
  int ra0 = mt * 256 + srow;       ra0 = ra0 < cnt ? ra0 : cnt - 1;
  int ra1 = mt * 256 + srow + 128; ra1 = ra1 < cnt ? ra1 : cnt - 1;
  const size_t aoff0 = (size_t)ra0 * KK + slo * 8;
  const size_t aoff1 = (size_t)ra1 * KK + slo * 8;
  const size_t boff0 = (size_t)srow * KK + slo * 8;
  const size_t boff1 = (size_t)(srow + 128) * KK + slo * 8;
  const int dst0 = wv * 512;        // u16 offset (wave-uniform; HW adds lane*16B)
  const int dst1 = wv * 512 + 4096;

  // frag-read swizzle: row = 16*m-base + lr so row&3 == lr&3 -> constant
  const int fsw = (lg ^ (lr & 3)) * 8;

  f32x4 acc[8][4];
#pragma unroll
  for (int m = 0; m < 8; ++m)
#pragma unroll
    for (int n = 0; n < 4; ++n) {
      acc[m][n][0] = 0.f; acc[m][n][1] = 0.f; acc[m][n][2] = 0.f; acc[m][n][3] = 0.f;
    }

  s16x8 fa[8], fb[2];
  auto RDFA = [&](const u16* buf) {
#pragma unroll
    for (int m = 0; m < 8; ++m)
      fa[m] = *(const s16x8*)(buf + (wm * 128 + m * 16 + lr) * 32 + fsw);
  };
  auto RDFB = [&](const u16* buf, int ng) {
#pragma unroll
    for (int n = 0; n < 2; ++n)
      fb[n] = *(const s16x8*)(buf + (wn * 64 + (ng * 2 + n) * 16 + lr) * 32 + fsw);
  };
  auto MF = [&](int ng) {
#pragma unroll
    for (int m = 0; m < 8; ++m)
#pragma unroll
      for (int n = 0; n < 2; ++n)
        acc[m][ng * 2 + n] =
            __builtin_amdgcn_mfma_f32_16x16x32_bf16(fa[m], fb[n], acc[m][ng * 2 + n], 0, 0, 0);
  };

#define BAR() __builtin_amdgcn_s_barrier()
#define SB() __builtin_amdgcn_sched_barrier(0)
#define WAITL0() asm volatile("s_waitcnt lgkmcnt(0)" ::: "memory")
#define WAITV4() asm volatile("s_waitcnt vmcnt(4)" ::: "memory")

  const int nk = KK / 64;

  // prologue: stage tile0's 4 half-tiles (order Ak0,Bk0,Ak1,Bk1)
  gload16(Abase + aoff0, &lds[0][0][0] + dst0);
  gload16(Abase + aoff1, &lds[0][0][0] + dst1);
  gload16(Bbase + boff0, &lds[0][1][0] + dst0);
  gload16(Bbase + boff1, &lds[0][1][0] + dst1);
  gload16(Abase + aoff0 + 32, &lds[0][2][0] + dst0);
  gload16(Abase + aoff1 + 32, &lds[0][2][0] + dst1);
  gload16(Bbase + boff0 + 32, &lds[0][3][0] + dst0);
  gload16(Bbase + boff1 + 32, &lds[0][3][0] + dst1);
  WAITV4(); SB(); BAR();  // Ak0,Bk0 landed CU-wide

  for (int t = 0; t < nk; ++t) {
    const int d = t & 1;
    const int nd = d ^ 1;
    const u16* A0 = &lds[d][0][0];
    const u16* B0 = &lds[d][1][0];
    const u16* A1 = &lds[d][2][0];
    const u16* B1 = &lds[d][3][0];
    const bool st = (t + 1 < nk);
    const size_t kadd = (size_t)(t + 1) * 64;

    // phase 0: ks0, n{0,1}; stage Ak0(t+1)
    RDFA(A0); RDFB(B0, 0);
    if (st) {
      gload16(Abase + aoff0 + kadd, &lds[nd][0][0] + dst0);
      gload16(Abase + aoff1 + kadd, &lds[nd][0][0] + dst1);
    }
    SB(); BAR(); WAITL0(); SB();
    __builtin_amdgcn_s_setprio(1); MF(0); __builtin_amdgcn_s_setprio(0);
    WAITV4(); SB(); BAR();

    // phase 1: ks0, n{2,3}; stage Bk0(t+1)
    RDFB(B0, 1);
    if (st) {
      gload16(Bbase + boff0 + kadd, &lds[nd][1][0] + dst0);
      gload16(Bbase + boff1 + kadd, &lds[nd][1][0] + dst1);
    }
    SB(); BAR(); WAITL0(); SB();
    __builtin_amdgcn_s_setprio(1); MF(1); __builtin_amdgcn_s_setprio(0);
    WAITV4(); SB(); BAR();

    // phase 2: ks1, n{0,1}; stage Ak1(t+1)
    RDFA(A1); RDFB(B1, 0);
    if (st) {
      gload16(Abase + aoff0 + kadd + 32, &lds[nd][2][0] + dst0);
      gload16(Abase + aoff1 + kadd + 32, &lds[nd][2][0] + dst1);
    }
    SB(); BAR(); WAITL0(); SB();
    __builtin_amdgcn_s_setprio(1); MF(0); __builtin_amdgcn_s_setprio(0);
    WAITV4(); SB(); BAR();

    // phase 3: ks1, n{2,3}; stage Bk1(t+1)
    RDFB(B1, 1);
    if (st) {
      gload16(Bbase + boff0 + kadd + 32, &lds[nd][3][0] + dst0);
      gload16(Bbase + boff1 + kadd + 32, &lds[nd][3][0] + dst1);
    }
    SB(); BAR(); WAITL0(); SB();
    __builtin_amdgcn_s_setprio(1); MF(1); __builtin_amdgcn_s_setprio(0);
    WAITV4(); SB(); BAR();
  }

  asm volatile("s_waitcnt vmcnt(0) lgkmcnt(0)" ::: "memory");
  SB();
  __syncthreads();

  // epilogue: bias (+gelu), repack bf16 via LDS (full 128 KB), coalesced stores
  u16* lT = &lds[0][0][0];
  float bv[4];
#pragma unroll
  for (int n = 0; n < 4; ++n)
    bv[n] = bias[(size_t)e * NN + nt * 256 + wn * 64 + n * 16 + lr];
#pragma unroll
  for (int m = 0; m < 8; ++m) {
#pragma unroll
    for (int r4 = 0; r4 < 4; ++r4) {
      int row = wm * 128 + m * 16 + lg * 4 + r4;
#pragma unroll
      for (int n = 0; n < 4; ++n) {
        int col = wn * 64 + n * 16 + lr;
        float v = acc[m][n][r4] + bv[n];
        if (PHASE == 1) v = gelu_fast(v);
        lT[row * 256 + col] = f2bf(v);
      }
    }
  }
  __syncthreads();
#pragma unroll
  for (int j = 0; j < 16; ++j) {
    int idx = j * 512 + tid;
    int row = idx >> 5;
    int cu = idx & 31;
    int grow = mt * 256 + row;
    if (grow < cnt) {
      uint4 v = ((const uint4*)lT)[idx];
      *(uint4*)(outp + (size_t)(moff + grow) * NN + nt * 256 + cu * 8) = v;
    }
  }
#undef BAR
#undef SB
#undef WAITL0
#undef WAITV4
}

// out[tok] = w0 * y[slot0] + w1 * y[slot1]
__global__ void combine_kernel(const u16* __restrict__ y, const int* __restrict__ tok_slot,
                               const float* __restrict__ tok_w, float* __restrict__ out) {
  int gid = blockIdx.x * blockDim.x + threadIdx.x;
  int n = gid >> 8;
  int c4 = (gid & 255) * 4;
  int s0 = tok_slot[n * 2], s1 = tok_slot[n * 2 + 1];
  float w0 = tok_w[n * 2], w1 = tok_w[n * 2 + 1];
  uint2 a = *(const uint2*)(y + (size_t)s0 * CDIM + c4);
  uint2 b = *(const uint2*)(y + (size_t)s1 * CDIM + c4);
  float4 o;
  o.x = w0 * bflo(a.x) + w1 * bflo(b.x);
  o.y = w0 * bfhi(a.x) + w1 * bfhi(b.x);
  o.z = w0 * bflo(a.y) + w1 * bflo(b.y);
  o.w = w0 * bfhi(a.y) + w1 * bfhi(b.y);
  *(float4*)(out + (size_t)n * CDIM + c4) = o;
}

extern "C" void kernel_launch(void* const* d_in, const int* in_sizes, int n_in,
                              void* d_out, int out_size, void* d_ws, size_t ws_size,
                              hipStream_t stream) {
  const float* x  = (const float*)d_in[0];
  const float* wg = (const float*)d_in[1];
  const float* w1 = (const float*)d_in[2];
  const float* b1 = (const float*)d_in[3];
  const float* w2 = (const float*)d_in[4];
  const float* b2 = (const float*)d_in[5];
  float* out = (float*)d_out;

  char* ws = (char*)d_ws;
  int* cnt  = (int*)ws;
  int* fill = cnt + 8;
  int* offs = cnt + 16;
  size_t off = 256;
  int*   tok_e    = (int*)(ws + off);   off += (size_t)NTOK * 2 * 4;
  float* tok_w    = (float*)(ws + off); off += (size_t)NTOK * 2 * 4;
  int*   slot_tok = (int*)(ws + off);   off += (size_t)NTOK * 2 * 4;
  int*   tok_slot = (int*)(ws + off);   off += (size_t)NTOK * 2 * 4;
  u16*   xg  = (u16*)(ws + off); off += (size_t)NTOK * 2 * CDIM * 2;
  u16*   h   = (u16*)(ws + off); off += (size_t)NTOK * 2 * HDIM * 2;
  u16*   y   = (u16*)(ws + off); off += (size_t)NTOK * 2 * CDIM * 2;
  u16*   w1t = (u16*)(ws + off); off += (size_t)ENUM * CDIM * HDIM * 2;
  u16*   w2t = (u16*)(ws + off); off += (size_t)ENUM * HDIM * CDIM * 2;

  hipMemsetAsync(cnt, 0, 64, stream);

  wconv_kernel<<<dim3(HDIM / 64, CDIM / 64, ENUM), 256, 0, stream>>>(w1, w1t, CDIM, HDIM);
  wconv_kernel<<<dim3(CDIM / 64, HDIM / 64, ENUM), 256, 0, stream>>>(w2, w2t, HDIM, CDIM);

  gate_kernel<<<NTOK / 4, 256, 0, stream>>>(x, wg, cnt, tok_e, tok_w);
  offsets_kernel<<<1, 64, 0, stream>>>(cnt, offs);
  assign_kernel<<<NTOK / 256, 256, 0, stream>>>(tok_e, offs, fill, slot_tok, tok_slot);
  gather_kernel<<<NTOK * 2, 256, 0, stream>>>(x, slot_tok, xg);

  moe_gemm<1, CDIM, HDIM, 16><<<ENUM * 64 * 16, 512, 0, stream>>>(
      xg, w1t, b1, h, cnt, offs);
  moe_gemm<2, HDIM, CDIM, 4><<<ENUM * 64 * 4, 512, 0, stream>>>(
      h, w2t, b2, y, cnt, offs);

  combine_kernel<<<NTOK, 256, 0, stream>>>(y, tok_slot, tok_w, out);
}

// Round 7
// 808.179 us; speedup vs baseline: 1.0292x; 1.0292x over previous
//
#include <hip/hip_runtime.h>

#define NTOK 8192
#define CDIM 1024
#define ENUM 8
#define HDIM 4096

typedef unsigned short u16;
typedef unsigned int u32;
typedef __attribute__((ext_vector_type(8))) short s16x8;
typedef __attribute__((ext_vector_type(4))) float f32x4;
typedef __attribute__((ext_vector_type(4))) u32 u32x4;

static __device__ __forceinline__ u16 f2bf(float f) {
  union { float f; u32 u; } v; v.f = f;
  u32 r = v.u + 0x7fffu + ((v.u >> 16) & 1u);
  return (u16)(r >> 16);
}
static __device__ __forceinline__ u32 pack2(float a, float b) {
  return (u32)f2bf(a) | ((u32)f2bf(b) << 16);
}
static __device__ __forceinline__ float bflo(u32 v) {
  union { u32 u; float f; } x; x.u = v << 16; return x.f;
}
static __device__ __forceinline__ float bfhi(u32 v) {
  union { u32 u; float f; } x; x.u = v & 0xffff0000u; return x.f;
}

typedef __attribute__((address_space(1))) const void gvoid;
typedef __attribute__((address_space(3))) void lvoid;
static __device__ __forceinline__ void gload16(const u16* g, u16* l) {
  __builtin_amdgcn_global_load_lds((gvoid*)g, (lvoid*)l, 16, 0, 0);
}

static __device__ __forceinline__ float gelu_fast(float v) {
  float u = v * (1.5957691216f + 0.1426929792f * v * v);
  return v / (1.f + __expf(-u));
}

// ---------------- weight convert + transpose: w[E][K][N] f32 -> wt[E][N][K] bf16 ----
__global__ void wconv_kernel(const float* __restrict__ w, u16* __restrict__ wt,
                             int K, int N) {
  __shared__ float lt[64][65];
  const int e = blockIdx.z, k0 = blockIdx.y * 64, n0 = blockIdx.x * 64;
  const float* src = w + (size_t)e * K * N;
  u16* dst = wt + (size_t)e * N * K;
  const int t = threadIdx.x;
  const int tr = t >> 4, tc = (t & 15) * 4;
#pragma unroll
  for (int i = 0; i < 4; ++i) {
    float4 v = *(const float4*)(src + (size_t)(k0 + tr + i * 16) * N + n0 + tc);
    lt[tr + i * 16][tc] = v.x; lt[tr + i * 16][tc + 1] = v.y;
    lt[tr + i * 16][tc + 2] = v.z; lt[tr + i * 16][tc + 3] = v.w;
  }
  __syncthreads();
#pragma unroll
  for (int i = 0; i < 4; ++i) {
    int n = tr + i * 16;
    uint2 o;
    o.x = pack2(lt[tc + 0][n], lt[tc + 1][n]);
    o.y = pack2(lt[tc + 2][n], lt[tc + 3][n]);
    *(uint2*)(dst + (size_t)(n0 + n) * K + k0 + tc) = o;
  }
}

// ---------------- gating ----------------
__global__ void gate_kernel(const float* __restrict__ x, const float* __restrict__ wg,
                            int* __restrict__ cnt, int* __restrict__ tok_e,
                            float* __restrict__ tok_w) {
  int gw = (blockIdx.x * blockDim.x + threadIdx.x) >> 6;
  int lane = threadIdx.x & 63;
  if (gw >= NTOK) return;
  const float* xr = x + (size_t)gw * CDIM;
  float acc[ENUM];
#pragma unroll
  for (int e = 0; e < ENUM; ++e) acc[e] = 0.f;
  for (int i = 0; i < CDIM / 64; ++i) {
    int c = i * 64 + lane;
    float xv = xr[c];
    float4 wa = *(const float4*)(wg + (size_t)c * ENUM);
    float4 wb = *(const float4*)(wg + (size_t)c * ENUM + 4);
    acc[0] += xv * wa.x; acc[1] += xv * wa.y; acc[2] += xv * wa.z; acc[3] += xv * wa.w;
    acc[4] += xv * wb.x; acc[5] += xv * wb.y; acc[6] += xv * wb.z; acc[7] += xv * wb.w;
  }
#pragma unroll
  for (int e = 0; e < ENUM; ++e) {
#pragma unroll
    for (int off = 32; off > 0; off >>= 1) acc[e] += __shfl_xor(acc[e], off);
  }
  if (lane == 0) {
    int i0 = 0; float v0 = acc[0];
#pragma unroll
    for (int e = 1; e < ENUM; ++e) if (acc[e] > v0) { v0 = acc[e]; i0 = e; }
    int i1 = -1; float v1 = -3.4e38f;
#pragma unroll
    for (int e = 0; e < ENUM; ++e) if (e != i0 && acc[e] > v1) { v1 = acc[e]; i1 = e; }
    float ex = expf(v1 - v0);
    float den = 1.f + ex;
    tok_e[gw * 2] = i0;     tok_w[gw * 2] = 1.f / den;
    tok_e[gw * 2 + 1] = i1; tok_w[gw * 2 + 1] = ex / den;
    atomicAdd(&cnt[i0], 1); atomicAdd(&cnt[i1], 1);
  }
}

__global__ void offsets_kernel(const int* __restrict__ cnt, int* __restrict__ offs) {
  if (threadIdx.x == 0 && blockIdx.x == 0) {
    int s = 0;
    for (int e = 0; e < ENUM; ++e) { offs[e] = s; s += cnt[e]; }
  }
}

__global__ void assign_kernel(const int* __restrict__ tok_e, const int* __restrict__ offs,
                              int* __restrict__ fill, int* __restrict__ slot_tok,
                              int* __restrict__ tok_slot) {
  int n = blockIdx.x * blockDim.x + threadIdx.x;
  if (n >= NTOK) return;
#pragma unroll
  for (int j = 0; j < 2; ++j) {
    int e = tok_e[n * 2 + j];
    int pos = atomicAdd(&fill[e], 1);
    int slot = offs[e] + pos;
    slot_tok[slot] = n;
    tok_slot[n * 2 + j] = slot;
  }
}

__global__ void gather_kernel(const float* __restrict__ x, const int* __restrict__ slot_tok,
                              u16* __restrict__ xg) {
  int gid = blockIdx.x * blockDim.x + threadIdx.x;
  int slot = gid >> 8;
  int c4 = (gid & 255) * 4;
  int tok = slot_tok[slot];
  float4 v = *(const float4*)(x + (size_t)tok * CDIM + c4);
  uint2 o; o.x = pack2(v.x, v.y); o.y = pack2(v.z, v.w);
  *(uint2*)(xg + (size_t)slot * CDIM + c4) = o;
}

// ---------------- expert GEMMs: 128(M) x 256(N) tile, BK=64, 4 waves (2x2) ----------
// A: bf16 [slots][K]; B^T: bf16 [E][N][K]. Per-wave 64x128 out (acc 4x8).
// Single-buffer stage->sync->compute->sync (R3-proven), 64 KB LDS -> 2 blocks/CU.
// Swizzle: oct ^= row&7 on source (linear gload_lds dest) and on ds_read octet.
// Outputs stored nontemporal (h/y are streams; keep weights resident in L3).
template <int PHASE>
__global__ __launch_bounds__(256, 2) void moe_gemm(
    const u16* __restrict__ Ag, const u16* __restrict__ Bt, const float* __restrict__ bias,
    u16* __restrict__ outp,
    const int* __restrict__ cnts, const int* __restrict__ offs,
    int K, int Nn) {
  const int e = blockIdx.z;
  const int cnt = cnts[e];
  const int mt = blockIdx.y;
  if (mt * 128 >= cnt) return;
  const int nt = blockIdx.x;
  const int moff = offs[e];
  const int tid = threadIdx.x;
  const int wv = tid >> 6, ln = tid & 63;
  const int lr = ln & 15, lg = ln >> 4;
  const int wm = wv >> 1, wn = wv & 1;

  __shared__ __align__(16) u16 lds[32768];  // 64 KB: A 16KB @0, B 32KB @8192
  u16* lA = lds;
  u16* lB = lds + 8192;

  const u16* Abase = Ag + (size_t)moff * K;
  const u16* Bbase = Bt + (size_t)e * Nn * K + (size_t)nt * 256 * K;

  // staging geometry: octet idx = c*256 + tid; row = idx>>3; src oct ^= row&7
  const int so8 = (((tid & 7) ^ ((tid >> 3) & 7))) * 8;  // swizzled k-offset (elems)
  const int rbase = tid >> 3;                            // 0..31
  size_t aoffs[4];
#pragma unroll
  for (int c = 0; c < 4; ++c) {
    int ra = mt * 128 + c * 32 + rbase;
    ra = ra < cnt ? ra : cnt - 1;  // clamp: padded rows discarded in epilogue
    aoffs[c] = (size_t)ra * K + so8;
  }
  size_t boffs[8];
#pragma unroll
  for (int c = 0; c < 8; ++c) boffs[c] = (size_t)(c * 32 + rbase) * K + so8;

  f32x4 acc[4][8];
#pragma unroll
  for (int m = 0; m < 4; ++m)
#pragma unroll
    for (int n = 0; n < 8; ++n) {
      acc[m][n][0] = 0.f; acc[m][n][1] = 0.f; acc[m][n][2] = 0.f; acc[m][n][3] = 0.f;
    }

  const int nk = K / 64;
  for (int kt = 0; kt < nk; ++kt) {
    const int kadd = kt * 64;
#pragma unroll
    for (int c = 0; c < 4; ++c)
      gload16(Abase + aoffs[c] + kadd, lA + (c * 256 + tid) * 8);
#pragma unroll
    for (int c = 0; c < 8; ++c)
      gload16(Bbase + boffs[c] + kadd, lB + (c * 256 + tid) * 8);
    __syncthreads();  // compiler drains vmcnt before barrier
#pragma unroll
    for (int ko = 0; ko < 2; ++ko) {
      const int ord = ((ko * 4 + lg) ^ (lr & 7)) * 8;
      s16x8 af[4], bfr[8];
#pragma unroll
      for (int m = 0; m < 4; ++m)
        af[m] = *(const s16x8*)(lA + (wm * 64 + m * 16 + lr) * 64 + ord);
#pragma unroll
      for (int n = 0; n < 8; ++n)
        bfr[n] = *(const s16x8*)(lB + (wn * 128 + n * 16 + lr) * 64 + ord);
#pragma unroll
      for (int m = 0; m < 4; ++m)
#pragma unroll
        for (int n = 0; n < 8; ++n)
          acc[m][n] = __builtin_amdgcn_mfma_f32_16x16x32_bf16(af[m], bfr[n], acc[m][n], 0, 0, 0);
    }
    __syncthreads();
  }

  // epilogue: bias (+gelu), pack bf16 into LDS tile [128][256], coalesced nt stores
  u16* lT = lds;  // full 64 KB
  float bv[8];
#pragma unroll
  for (int n = 0; n < 8; ++n)
    bv[n] = bias[(size_t)e * Nn + nt * 256 + wn * 128 + n * 16 + lr];
#pragma unroll
  for (int m = 0; m < 4; ++m) {
#pragma unroll
    for (int r4 = 0; r4 < 4; ++r4) {
      int row = wm * 64 + m * 16 + lg * 4 + r4;
#pragma unroll
      for (int n = 0; n < 8; ++n) {
        int col = wn * 128 + n * 16 + lr;
        float v = acc[m][n][r4] + bv[n];
        if (PHASE == 1) v = gelu_fast(v);
        lT[row * 256 + col] = f2bf(v);
      }
    }
  }
  __syncthreads();
#pragma unroll
  for (int j = 0; j < 16; ++j) {
    int idx = j * 256 + tid;     // u32x4 index; 4096 total (32 per row)
    int row = idx >> 5;
    int cu = idx & 31;
    int grow = mt * 128 + row;
    if (grow < cnt) {
      u32x4 v = ((const u32x4*)lT)[idx];
      __builtin_nontemporal_store(
          v, (u32x4*)(outp + (size_t)(moff + grow) * Nn + nt * 256 + cu * 8));
    }
  }
}

// out[tok] = w0 * y[slot0] + w1 * y[slot1]
__global__ void combine_kernel(const u16* __restrict__ y, const int* __restrict__ tok_slot,
                               const float* __restrict__ tok_w, float* __restrict__ out) {
  int gid = blockIdx.x * blockDim.x + threadIdx.x;
  int n = gid >> 8;
  int c4 = (gid & 255) * 4;
  int s0 = tok_slot[n * 2], s1 = tok_slot[n * 2 + 1];
  float w0 = tok_w[n * 2], w1 = tok_w[n * 2 + 1];
  uint2 a = *(const uint2*)(y + (size_t)s0 * CDIM + c4);
  uint2 b = *(const uint2*)(y + (size_t)s1 * CDIM + c4);
  float4 o;
  o.x = w0 * bflo(a.x) + w1 * bflo(b.x);
  o.y = w0 * bfhi(a.x) + w1 * bfhi(b.x);
  o.z = w0 * bflo(a.y) + w1 * bflo(b.y);
  o.w = w0 * bfhi(a.y) + w1 * bfhi(b.y);
  *(float4*)(out + (size_t)n * CDIM + c4) = o;
}

extern "C" void kernel_launch(void* const* d_in, const int* in_sizes, int n_in,
                              void* d_out, int out_size, void* d_ws, size_t ws_size,
                              hipStream_t stream) {
  const float* x  = (const float*)d_in[0];
  const float* wg = (const float*)d_in[1];
  const float* w1 = (const float*)d_in[2];
  const float* b1 = (const float*)d_in[3];
  const float* w2 = (const float*)d_in[4];
  const float* b2 = (const float*)d_in[5];
  float* out = (float*)d_out;

  char* ws = (char*)d_ws;
  int* cnt  = (int*)ws;
  int* fill = cnt + 8;
  int* offs = cnt + 16;
  size_t off = 256;
  int*   tok_e    = (int*)(ws + off);   off += (size_t)NTOK * 2 * 4;
  float* tok_w    = (float*)(ws + off); off += (size_t)NTOK * 2 * 4;
  int*   slot_tok = (int*)(ws + off);   off += (size_t)NTOK * 2 * 4;
  int*   tok_slot = (int*)(ws + off);   off += (size_t)NTOK * 2 * 4;
  u16*   xg  = (u16*)(ws + off); off += (size_t)NTOK * 2 * CDIM * 2;
  u16*   h   = (u16*)(ws + off); off += (size_t)NTOK * 2 * HDIM * 2;
  u16*   y   = (u16*)(ws + off); off += (size_t)NTOK * 2 * CDIM * 2;
  u16*   w1t = (u16*)(ws + off); off += (size_t)ENUM * CDIM * HDIM * 2;
  u16*   w2t = (u16*)(ws + off); off += (size_t)ENUM * HDIM * CDIM * 2;

  hipMemsetAsync(cnt, 0, 64, stream);

  wconv_kernel<<<dim3(HDIM / 64, CDIM / 64, ENUM), 256, 0, stream>>>(w1, w1t, CDIM, HDIM);
  wconv_kernel<<<dim3(CDIM / 64, HDIM / 64, ENUM), 256, 0, stream>>>(w2, w2t, HDIM, CDIM);

  gate_kernel<<<NTOK / 4, 256, 0, stream>>>(x, wg, cnt, tok_e, tok_w);
  offsets_kernel<<<1, 64, 0, stream>>>(cnt, offs);
  assign_kernel<<<NTOK / 256, 256, 0, stream>>>(tok_e, offs, fill, slot_tok, tok_slot);
  gather_kernel<<<NTOK * 2, 256, 0, stream>>>(x, slot_tok, xg);

  moe_gemm<1><<<dim3(HDIM / 256, NTOK / 128, ENUM), 256, 0, stream>>>(
      xg, w1t, b1, h, cnt, offs, CDIM, HDIM);
  moe_gemm<2><<<dim3(CDIM / 256, NTOK / 128, ENUM), 256, 0, stream>>>(
      h, w2t, b2, y, cnt, offs, HDIM, CDIM);

  combine_kernel<<<NTOK, 256, 0, stream>>>(y, tok_slot, tok_w, out);
}

// Round 8
// 767.982 us; speedup vs baseline: 1.0831x; 1.0523x over previous
//
#include <hip/hip_runtime.h>

#define NTOK 8192
#define CDIM 1024
#define ENUM 8
#define HDIM 4096

typedef unsigned short u16;
typedef unsigned int u32;
typedef __attribute__((ext_vector_type(8))) short s16x8;
typedef __attribute__((ext_vector_type(4))) float f32x4;
typedef __attribute__((ext_vector_type(4))) u32 u32x4;
typedef __attribute__((ext_vector_type(2))) u32 u32x2;

static __device__ __forceinline__ u16 f2bf(float f) {
  union { float f; u32 u; } v; v.f = f;
  u32 r = v.u + 0x7fffu + ((v.u >> 16) & 1u);
  return (u16)(r >> 16);
}
static __device__ __forceinline__ u32 pack2(float a, float b) {
  return (u32)f2bf(a) | ((u32)f2bf(b) << 16);
}
static __device__ __forceinline__ float bflo(u32 v) {
  union { u32 u; float f; } x; x.u = v << 16; return x.f;
}
static __device__ __forceinline__ float bfhi(u32 v) {
  union { u32 u; float f; } x; x.u = v & 0xffff0000u; return x.f;
}

typedef __attribute__((address_space(1))) const void gvoid;
typedef __attribute__((address_space(3))) void lvoid;
static __device__ __forceinline__ void gload16(const u16* g, u16* l) {
  __builtin_amdgcn_global_load_lds((gvoid*)g, (lvoid*)l, 16, 0, 0);
}

static __device__ __forceinline__ float gelu_fast(float v) {
  float u = v * (1.5957691216f + 0.1426929792f * v * v);
  return v / (1.f + __expf(-u));
}

// ---------------- weight convert + transpose: w[E][K][N] f32 -> wt[E][N][K] bf16 ----
// NT loads: the 268 MB f32 weight stream is read-once; keep it out of L3.
__global__ void wconv_kernel(const float* __restrict__ w, u16* __restrict__ wt,
                             int K, int N) {
  __shared__ float lt[64][65];
  const int e = blockIdx.z, k0 = blockIdx.y * 64, n0 = blockIdx.x * 64;
  const float* src = w + (size_t)e * K * N;
  u16* dst = wt + (size_t)e * N * K;
  const int t = threadIdx.x;
  const int tr = t >> 4, tc = (t & 15) * 4;
#pragma unroll
  for (int i = 0; i < 4; ++i) {
    f32x4 v = __builtin_nontemporal_load(
        (const f32x4*)(src + (size_t)(k0 + tr + i * 16) * N + n0 + tc));
    lt[tr + i * 16][tc] = v.x; lt[tr + i * 16][tc + 1] = v.y;
    lt[tr + i * 16][tc + 2] = v.z; lt[tr + i * 16][tc + 3] = v.w;
  }
  __syncthreads();
#pragma unroll
  for (int i = 0; i < 4; ++i) {
    int n = tr + i * 16;
    uint2 o;
    o.x = pack2(lt[tc + 0][n], lt[tc + 1][n]);
    o.y = pack2(lt[tc + 2][n], lt[tc + 3][n]);
    *(uint2*)(dst + (size_t)(n0 + n) * K + k0 + tc) = o;
  }
}

// ---------------- gating ----------------
__global__ void gate_kernel(const float* __restrict__ x, const float* __restrict__ wg,
                            int* __restrict__ cnt, int* __restrict__ tok_e,
                            float* __restrict__ tok_w) {
  int gw = (blockIdx.x * blockDim.x + threadIdx.x) >> 6;
  int lane = threadIdx.x & 63;
  if (gw >= NTOK) return;
  const float* xr = x + (size_t)gw * CDIM;
  float acc[ENUM];
#pragma unroll
  for (int e = 0; e < ENUM; ++e) acc[e] = 0.f;
  for (int i = 0; i < CDIM / 64; ++i) {
    int c = i * 64 + lane;
    float xv = xr[c];
    float4 wa = *(const float4*)(wg + (size_t)c * ENUM);
    float4 wb = *(const float4*)(wg + (size_t)c * ENUM + 4);
    acc[0] += xv * wa.x; acc[1] += xv * wa.y; acc[2] += xv * wa.z; acc[3] += xv * wa.w;
    acc[4] += xv * wb.x; acc[5] += xv * wb.y; acc[6] += xv * wb.z; acc[7] += xv * wb.w;
  }
#pragma unroll
  for (int e = 0; e < ENUM; ++e) {
#pragma unroll
    for (int off = 32; off > 0; off >>= 1) acc[e] += __shfl_xor(acc[e], off);
  }
  if (lane == 0) {
    int i0 = 0; float v0 = acc[0];
#pragma unroll
    for (int e = 1; e < ENUM; ++e) if (acc[e] > v0) { v0 = acc[e]; i0 = e; }
    int i1 = -1; float v1 = -3.4e38f;
#pragma unroll
    for (int e = 0; e < ENUM; ++e) if (e != i0 && acc[e] > v1) { v1 = acc[e]; i1 = e; }
    float ex = expf(v1 - v0);
    float den = 1.f + ex;
    tok_e[gw * 2] = i0;     tok_w[gw * 2] = 1.f / den;
    tok_e[gw * 2 + 1] = i1; tok_w[gw * 2 + 1] = ex / den;
    atomicAdd(&cnt[i0], 1); atomicAdd(&cnt[i1], 1);
  }
}

__global__ void offsets_kernel(const int* __restrict__ cnt, int* __restrict__ offs) {
  if (threadIdx.x == 0 && blockIdx.x == 0) {
    int s = 0;
    for (int e = 0; e < ENUM; ++e) { offs[e] = s; s += cnt[e]; }
  }
}

__global__ void assign_kernel(const int* __restrict__ tok_e, const int* __restrict__ offs,
                              int* __restrict__ fill, int* __restrict__ slot_tok,
                              int* __restrict__ tok_slot) {
  int n = blockIdx.x * blockDim.x + threadIdx.x;
  if (n >= NTOK) return;
#pragma unroll
  for (int j = 0; j < 2; ++j) {
    int e = tok_e[n * 2 + j];
    int pos = atomicAdd(&fill[e], 1);
    int slot = offs[e] + pos;
    slot_tok[slot] = n;
    tok_slot[n * 2 + j] = slot;
  }
}

__global__ void gather_kernel(const float* __restrict__ x, const int* __restrict__ slot_tok,
                              u16* __restrict__ xg) {
  int gid = blockIdx.x * blockDim.x + threadIdx.x;
  int slot = gid >> 8;
  int c4 = (gid & 255) * 4;
  int tok = slot_tok[slot];
  float4 v = *(const float4*)(x + (size_t)tok * CDIM + c4);
  uint2 o; o.x = pack2(v.x, v.y); o.y = pack2(v.z, v.w);
  *(uint2*)(xg + (size_t)slot * CDIM + c4) = o;
}

// ---------------- expert GEMMs (R3-proven 128x128, BK=64, 4 waves) ----------------
// A: bf16 [slots][K]; B^T: bf16 [E][N][K]. global_load_lds with source-side XOR
// octet swizzle (linear LDS dest); ds_reads XOR back. ~3 waves/SIMD occupancy.
// Epilogue: LDS-repack + NONTEMPORAL uint4 stores (h/y are streams; keep the
// weight panels resident in L3 -> cut B re-fetch from HBM).
template <int PHASE>
__global__ __launch_bounds__(256, 2) void moe_gemm(
    const u16* __restrict__ Ag, const u16* __restrict__ Bt, const float* __restrict__ bias,
    u16* __restrict__ outp,
    const int* __restrict__ cnts, const int* __restrict__ offs,
    int K, int Nn) {
  const int e = blockIdx.z;
  const int cnt = cnts[e];
  const int mt = blockIdx.y;
  if (mt * 128 >= cnt) return;
  const int nt = blockIdx.x;
  const int moff = offs[e];
  const int tid = threadIdx.x;
  const int wv = tid >> 6, ln = tid & 63;
  const int lr = ln & 15, lg = ln >> 4;
  const int wm = wv >> 1, wn = wv & 1;

  __shared__ __align__(16) u16 lds[2][128 * 64];
  u16* lA = lds[0];
  u16* lB = lds[1];

  const u16* Abase = Ag + (size_t)moff * K;
  const u16* Bbase = Bt + (size_t)e * Nn * K + (size_t)nt * 128 * K;

  const int srow = ln >> 3;                       // row-in-chunk 0..7
  const int sk = (((ln & 7) ^ srow)) * 8;         // swizzled source octet offset

  f32x4 acc[4][4];
#pragma unroll
  for (int m = 0; m < 4; ++m)
#pragma unroll
    for (int n = 0; n < 4; ++n) {
      acc[m][n][0] = 0.f; acc[m][n][1] = 0.f; acc[m][n][2] = 0.f; acc[m][n][3] = 0.f;
    }

  const int nk = K / 64;
  for (int kt = 0; kt < nk; ++kt) {
#pragma unroll
    for (int i = 0; i < 4; ++i) {
      int c = wv * 4 + i;
      int ra = mt * 128 + c * 8 + srow;
      ra = ra < cnt ? ra : cnt - 1;  // clamp: padded rows discarded in epilogue
      gload16(Abase + (size_t)ra * K + kt * 64 + sk, lA + c * 512);
      gload16(Bbase + (size_t)(c * 8 + srow) * K + kt * 64 + sk, lB + c * 512);
    }
    __syncthreads();
#pragma unroll
    for (int ko = 0; ko < 2; ++ko) {
      s16x8 af[4], bfr[4];
      const int lsw = lr & 7;
#pragma unroll
      for (int m = 0; m < 4; ++m)
        af[m] = *(const s16x8*)(lA + (wm * 64 + m * 16 + lr) * 64 + ((ko * 4 + lg) ^ lsw) * 8);
#pragma unroll
      for (int n = 0; n < 4; ++n)
        bfr[n] = *(const s16x8*)(lB + (wn * 64 + n * 16 + lr) * 64 + ((ko * 4 + lg) ^ lsw) * 8);
#pragma unroll
      for (int m = 0; m < 4; ++m)
#pragma unroll
        for (int n = 0; n < 4; ++n)
          acc[m][n] = __builtin_amdgcn_mfma_f32_16x16x32_bf16(af[m], bfr[n], acc[m][n], 0, 0, 0);
    }
    __syncthreads();
  }

  // epilogue: bias (+gelu), pack bf16 into LDS tile [128][128], coalesced NT store
  u16* lT = lds[0];  // 32 KB contiguous
  float bv[4];
#pragma unroll
  for (int n = 0; n < 4; ++n) bv[n] = bias[(size_t)e * Nn + nt * 128 + wn * 64 + n * 16 + lr];
#pragma unroll
  for (int m = 0; m < 4; ++m) {
#pragma unroll
    for (int r = 0; r < 4; ++r) {
      int row = wm * 64 + m * 16 + lg * 4 + r;
#pragma unroll
      for (int n = 0; n < 4; ++n) {
        int col = wn * 64 + n * 16 + lr;
        float v = acc[m][n][r] + bv[n];
        if (PHASE == 1) v = gelu_fast(v);
        lT[row * 128 + col] = f2bf(v);
      }
    }
  }
  __syncthreads();
#pragma unroll
  for (int j = 0; j < 8; ++j) {
    int u = j * 256 + tid;           // u32x4 index into 128x128 tile
    int row = u >> 4;                // 16 u32x4 per row
    int colb = (u & 15) * 8;
    int grow = mt * 128 + row;
    if (grow < cnt) {
      u32x4 v = ((const u32x4*)lT)[u];
      __builtin_nontemporal_store(
          v, (u32x4*)(outp + (size_t)(moff + grow) * Nn + nt * 128 + colb));
    }
  }
}

// out[tok] = w0 * y[slot0] + w1 * y[slot1]   (y read-once -> NT loads)
__global__ void combine_kernel(const u16* __restrict__ y, const int* __restrict__ tok_slot,
                               const float* __restrict__ tok_w, float* __restrict__ out) {
  int gid = blockIdx.x * blockDim.x + threadIdx.x;
  int n = gid >> 8;
  int c4 = (gid & 255) * 4;
  int s0 = tok_slot[n * 2], s1 = tok_slot[n * 2 + 1];
  float w0 = tok_w[n * 2], w1 = tok_w[n * 2 + 1];
  u32x2 a = __builtin_nontemporal_load((const u32x2*)(y + (size_t)s0 * CDIM + c4));
  u32x2 b = __builtin_nontemporal_load((const u32x2*)(y + (size_t)s1 * CDIM + c4));
  float4 o;
  o.x = w0 * bflo(a.x) + w1 * bflo(b.x);
  o.y = w0 * bfhi(a.x) + w1 * bfhi(b.x);
  o.z = w0 * bflo(a.y) + w1 * bflo(b.y);
  o.w = w0 * bfhi(a.y) + w1 * bfhi(b.y);
  *(float4*)(out + (size_t)n * CDIM + c4) = o;
}

extern "C" void kernel_launch(void* const* d_in, const int* in_sizes, int n_in,
                              void* d_out, int out_size, void* d_ws, size_t ws_size,
                              hipStream_t stream) {
  const float* x  = (const float*)d_in[0];
  const float* wg = (const float*)d_in[1];
  const float* w1 = (const float*)d_in[2];
  const float* b1 = (const float*)d_in[3];
  const float* w2 = (const float*)d_in[4];
  const float* b2 = (const float*)d_in[5];
  float* out = (float*)d_out;

  char* ws = (char*)d_ws;
  int* cnt  = (int*)ws;
  int* fill = cnt + 8;
  int* offs = cnt + 16;
  size_t off = 256;
  int*   tok_e    = (int*)(ws + off);   off += (size_t)NTOK * 2 * 4;
  float* tok_w    = (float*)(ws + off); off += (size_t)NTOK * 2 * 4;
  int*   slot_tok = (int*)(ws + off);   off += (size_t)NTOK * 2 * 4;
  int*   tok_slot = (int*)(ws + off);   off += (size_t)NTOK * 2 * 4;
  u16*   xg  = (u16*)(ws + off); off += (size_t)NTOK * 2 * CDIM * 2;
  u16*   h   = (u16*)(ws + off); off += (size_t)NTOK * 2 * HDIM * 2;
  u16*   y   = (u16*)(ws + off); off += (size_t)NTOK * 2 * CDIM * 2;
  u16*   w1t = (u16*)(ws + off); off += (size_t)ENUM * CDIM * HDIM * 2;
  u16*   w2t = (u16*)(ws + off); off += (size_t)ENUM * HDIM * CDIM * 2;

  hipMemsetAsync(cnt, 0, 64, stream);

  wconv_kernel<<<dim3(HDIM / 64, CDIM / 64, ENUM), 256, 0, stream>>>(w1, w1t, CDIM, HDIM);
  wconv_kernel<<<dim3(CDIM / 64, HDIM / 64, ENUM), 256, 0, stream>>>(w2, w2t, HDIM, CDIM);

  gate_kernel<<<NTOK / 4, 256, 0, stream>>>(x, wg, cnt, tok_e, tok_w);
  offsets_kernel<<<1, 64, 0, stream>>>(cnt, offs);
  assign_kernel<<<NTOK / 256, 256, 0, stream>>>(tok_e, offs, fill, slot_tok, tok_slot);
  gather_kernel<<<NTOK * 2, 256, 0, stream>>>(x, slot_tok, xg);

  moe_gemm<1><<<dim3(HDIM / 128, NTOK / 128, ENUM), 256, 0, stream>>>(
      xg, w1t, b1, h, cnt, offs, CDIM, HDIM);
  moe_gemm<2><<<dim3(CDIM / 128, NTOK / 128, ENUM), 256, 0, stream>>>(
      h, w2t, b2, y, cnt, offs, HDIM, CDIM);

  combine_kernel<<<NTOK, 256, 0, stream>>>(y, tok_slot, tok_w, out);
}

// Round 9
// 757.668 us; speedup vs baseline: 1.0978x; 1.0136x over previous
//
#include <hip/hip_runtime.h>

#define NTOK 8192
#define CDIM 1024
#define ENUM 8
#define HDIM 4096

typedef unsigned short u16;
typedef unsigned int u32;
typedef __attribute__((ext_vector_type(8))) short s16x8;
typedef __attribute__((ext_vector_type(4))) float f32x4;
typedef __attribute__((ext_vector_type(4))) u32 u32x4;
typedef __attribute__((ext_vector_type(2))) u32 u32x2;

static __device__ __forceinline__ u16 f2bf(float f) {
  union { float f; u32 u; } v; v.f = f;
  u32 r = v.u + 0x7fffu + ((v.u >> 16) & 1u);
  return (u16)(r >> 16);
}
static __device__ __forceinline__ u32 pack2(float a, float b) {
  return (u32)f2bf(a) | ((u32)f2bf(b) << 16);
}
static __device__ __forceinline__ float bflo(u32 v) {
  union { u32 u; float f; } x; x.u = v << 16; return x.f;
}
static __device__ __forceinline__ float bfhi(u32 v) {
  union { u32 u; float f; } x; x.u = v & 0xffff0000u; return x.f;
}

typedef __attribute__((address_space(1))) const void gvoid;
typedef __attribute__((address_space(3))) void lvoid;
static __device__ __forceinline__ void gload16(const u16* g, u16* l) {
  __builtin_amdgcn_global_load_lds((gvoid*)g, (lvoid*)l, 16, 0, 0);
}

static __device__ __forceinline__ float gelu_fast(float v) {
  float u = v * (1.5957691216f + 0.1426929792f * v * v);
  return v / (1.f + __expf(-u));
}

// ---------------- weight convert + transpose: w[E][K][N] f32 -> wt[E][N][K] bf16 ----
__global__ void wconv_kernel(const float* __restrict__ w, u16* __restrict__ wt,
                             int K, int N) {
  __shared__ float lt[64][65];
  const int e = blockIdx.z, k0 = blockIdx.y * 64, n0 = blockIdx.x * 64;
  const float* src = w + (size_t)e * K * N;
  u16* dst = wt + (size_t)e * N * K;
  const int t = threadIdx.x;
  const int tr = t >> 4, tc = (t & 15) * 4;
#pragma unroll
  for (int i = 0; i < 4; ++i) {
    f32x4 v = __builtin_nontemporal_load(
        (const f32x4*)(src + (size_t)(k0 + tr + i * 16) * N + n0 + tc));
    lt[tr + i * 16][tc] = v.x; lt[tr + i * 16][tc + 1] = v.y;
    lt[tr + i * 16][tc + 2] = v.z; lt[tr + i * 16][tc + 3] = v.w;
  }
  __syncthreads();
#pragma unroll
  for (int i = 0; i < 4; ++i) {
    int n = tr + i * 16;
    uint2 o;
    o.x = pack2(lt[tc + 0][n], lt[tc + 1][n]);
    o.y = pack2(lt[tc + 2][n], lt[tc + 3][n]);
    *(uint2*)(dst + (size_t)(n0 + n) * K + k0 + tc) = o;
  }
}

// ---------------- gating ----------------
__global__ void gate_kernel(const float* __restrict__ x, const float* __restrict__ wg,
                            int* __restrict__ cnt, int* __restrict__ tok_e,
                            float* __restrict__ tok_w) {
  int gw = (blockIdx.x * blockDim.x + threadIdx.x) >> 6;
  int lane = threadIdx.x & 63;
  if (gw >= NTOK) return;
  const float* xr = x + (size_t)gw * CDIM;
  float acc[ENUM];
#pragma unroll
  for (int e = 0; e < ENUM; ++e) acc[e] = 0.f;
  for (int i = 0; i < CDIM / 64; ++i) {
    int c = i * 64 + lane;
    float xv = xr[c];
    float4 wa = *(const float4*)(wg + (size_t)c * ENUM);
    float4 wb = *(const float4*)(wg + (size_t)c * ENUM + 4);
    acc[0] += xv * wa.x; acc[1] += xv * wa.y; acc[2] += xv * wa.z; acc[3] += xv * wa.w;
    acc[4] += xv * wb.x; acc[5] += xv * wb.y; acc[6] += xv * wb.z; acc[7] += xv * wb.w;
  }
#pragma unroll
  for (int e = 0; e < ENUM; ++e) {
#pragma unroll
    for (int off = 32; off > 0; off >>= 1) acc[e] += __shfl_xor(acc[e], off);
  }
  if (lane == 0) {
    int i0 = 0; float v0 = acc[0];
#pragma unroll
    for (int e = 1; e < ENUM; ++e) if (acc[e] > v0) { v0 = acc[e]; i0 = e; }
    int i1 = -1; float v1 = -3.4e38f;
#pragma unroll
    for (int e = 0; e < ENUM; ++e) if (e != i0 && acc[e] > v1) { v1 = acc[e]; i1 = e; }
    float ex = expf(v1 - v0);
    float den = 1.f + ex;
    tok_e[gw * 2] = i0;     tok_w[gw * 2] = 1.f / den;
    tok_e[gw * 2 + 1] = i1; tok_w[gw * 2 + 1] = ex / den;
    atomicAdd(&cnt[i0], 1); atomicAdd(&cnt[i1], 1);
  }
}

__global__ void offsets_kernel(const int* __restrict__ cnt, int* __restrict__ offs) {
  if (threadIdx.x == 0 && blockIdx.x == 0) {
    int s = 0;
    for (int e = 0; e < ENUM; ++e) { offs[e] = s; s += cnt[e]; }
  }
}

__global__ void assign_kernel(const int* __restrict__ tok_e, const int* __restrict__ offs,
                              int* __restrict__ fill, int* __restrict__ slot_tok,
                              int* __restrict__ tok_slot) {
  int n = blockIdx.x * blockDim.x + threadIdx.x;
  if (n >= NTOK) return;
#pragma unroll
  for (int j = 0; j < 2; ++j) {
    int e = tok_e[n * 2 + j];
    int pos = atomicAdd(&fill[e], 1);
    int slot = offs[e] + pos;
    slot_tok[slot] = n;
    tok_slot[n * 2 + j] = slot;
  }
}

__global__ void gather_kernel(const float* __restrict__ x, const int* __restrict__ slot_tok,
                              u16* __restrict__ xg) {
  int gid = blockIdx.x * blockDim.x + threadIdx.x;
  int slot = gid >> 8;
  int c4 = (gid & 255) * 4;
  int tok = slot_tok[slot];
  float4 v = *(const float4*)(x + (size_t)tok * CDIM + c4);
  uint2 o; o.x = pack2(v.x, v.y); o.y = pack2(v.z, v.w);
  *(uint2*)(xg + (size_t)slot * CDIM + c4) = o;
}

// ---------------- expert GEMMs (R3-proven 128x128, BK=64, 4 waves) ----------------
// + XCD-chunked block swizzle: within an expert, flat r -> XCD k=r%8 (HW round-robin,
// per-expert block count % 8 == 0), inner i=r/8. XCD k owns mt-chunk (k+e)%8
// (8 mt-rows x all nt, mt-fastest inner) -> per-XCD L2 working set ~4 MB
// (8 A-stripes hot + rolling B-slices); per-expert rotation balances XCDs.
template <int PHASE>
__global__ __launch_bounds__(256, 2) void moe_gemm(
    const u16* __restrict__ Ag, const u16* __restrict__ Bt, const float* __restrict__ bias,
    u16* __restrict__ outp,
    const int* __restrict__ cnts, const int* __restrict__ offs,
    int K, int Nn) {
  const int e = blockIdx.z;
  const int cnt = cnts[e];
  // swizzle (gridDim.y == 64, divisible by 8)
  {
  }
  const int NT = gridDim.x;
  const int MTC = gridDim.y >> 3;               // 8
  const int r = blockIdx.y * NT + blockIdx.x;   // launch-order flat (x fastest)
  const int k = r & 7;                          // XCD id
  const int i = r >> 3;                         // inner
  const int ck = (k + e) & 7;                   // rotated chunk for balance
  const int mt = ck * MTC + (i % MTC);
  const int nt = i / MTC;
  if (mt * 128 >= cnt) return;
  const int moff = offs[e];
  const int tid = threadIdx.x;
  const int wv = tid >> 6, ln = tid & 63;
  const int lr = ln & 15, lg = ln >> 4;
  const int wm = wv >> 1, wn = wv & 1;

  __shared__ __align__(16) u16 lds[2][128 * 64];
  u16* lA = lds[0];
  u16* lB = lds[1];

  const u16* Abase = Ag + (size_t)moff * K;
  const u16* Bbase = Bt + (size_t)e * Nn * K + (size_t)nt * 128 * K;

  const int srow = ln >> 3;                       // row-in-chunk 0..7
  const int sk = (((ln & 7) ^ srow)) * 8;         // swizzled source octet offset

  f32x4 acc[4][4];
#pragma unroll
  for (int m = 0; m < 4; ++m)
#pragma unroll
    for (int n = 0; n < 4; ++n) {
      acc[m][n][0] = 0.f; acc[m][n][1] = 0.f; acc[m][n][2] = 0.f; acc[m][n][3] = 0.f;
    }

  const int nk = K / 64;
  for (int kt = 0; kt < nk; ++kt) {
#pragma unroll
    for (int i4 = 0; i4 < 4; ++i4) {
      int c = wv * 4 + i4;
      int ra = mt * 128 + c * 8 + srow;
      ra = ra < cnt ? ra : cnt - 1;  // clamp: padded rows discarded in epilogue
      gload16(Abase + (size_t)ra * K + kt * 64 + sk, lA + c * 512);
      gload16(Bbase + (size_t)(c * 8 + srow) * K + kt * 64 + sk, lB + c * 512);
    }
    __syncthreads();
#pragma unroll
    for (int ko = 0; ko < 2; ++ko) {
      s16x8 af[4], bfr[4];
      const int lsw = lr & 7;
#pragma unroll
      for (int m = 0; m < 4; ++m)
        af[m] = *(const s16x8*)(lA + (wm * 64 + m * 16 + lr) * 64 + ((ko * 4 + lg) ^ lsw) * 8);
#pragma unroll
      for (int n = 0; n < 4; ++n)
        bfr[n] = *(const s16x8*)(lB + (wn * 64 + n * 16 + lr) * 64 + ((ko * 4 + lg) ^ lsw) * 8);
#pragma unroll
      for (int m = 0; m < 4; ++m)
#pragma unroll
        for (int n = 0; n < 4; ++n)
          acc[m][n] = __builtin_amdgcn_mfma_f32_16x16x32_bf16(af[m], bfr[n], acc[m][n], 0, 0, 0);
    }
    __syncthreads();
  }

  // epilogue: bias (+gelu), pack bf16 into LDS tile [128][128], coalesced store
  u16* lT = lds[0];
  float bv[4];
#pragma unroll
  for (int n = 0; n < 4; ++n) bv[n] = bias[(size_t)e * Nn + nt * 128 + wn * 64 + n * 16 + lr];
#pragma unroll
  for (int m = 0; m < 4; ++m) {
#pragma unroll
    for (int r4 = 0; r4 < 4; ++r4) {
      int row = wm * 64 + m * 16 + lg * 4 + r4;
#pragma unroll
      for (int n = 0; n < 4; ++n) {
        int col = wn * 64 + n * 16 + lr;
        float v = acc[m][n][r4] + bv[n];
        if (PHASE == 1) v = gelu_fast(v);
        lT[row * 128 + col] = f2bf(v);
      }
    }
  }
  __syncthreads();
#pragma unroll
  for (int j = 0; j < 8; ++j) {
    int u = j * 256 + tid;           // u32x4 index into 128x128 tile
    int row = u >> 4;                // 16 u32x4 per row
    int colb = (u & 15) * 8;
    int grow = mt * 128 + row;
    if (grow < cnt) {
      u32x4 v = ((const u32x4*)lT)[u];
      *(u32x4*)(outp + (size_t)(moff + grow) * Nn + nt * 128 + colb) = v;
    }
  }
}

// out[tok] = w0 * y[slot0] + w1 * y[slot1]   (y read-once -> NT loads)
__global__ void combine_kernel(const u16* __restrict__ y, const int* __restrict__ tok_slot,
                               const float* __restrict__ tok_w, float* __restrict__ out) {
  int gid = blockIdx.x * blockDim.x + threadIdx.x;
  int n = gid >> 8;
  int c4 = (gid & 255) * 4;
  int s0 = tok_slot[n * 2], s1 = tok_slot[n * 2 + 1];
  float w0 = tok_w[n * 2], w1 = tok_w[n * 2 + 1];
  u32x2 a = __builtin_nontemporal_load((const u32x2*)(y + (size_t)s0 * CDIM + c4));
  u32x2 b = __builtin_nontemporal_load((const u32x2*)(y + (size_t)s1 * CDIM + c4));
  float4 o;
  o.x = w0 * bflo(a.x) + w1 * bflo(b.x);
  o.y = w0 * bfhi(a.x) + w1 * bfhi(b.x);
  o.z = w0 * bflo(a.y) + w1 * bflo(b.y);
  o.w = w0 * bfhi(a.y) + w1 * bfhi(b.y);
  *(float4*)(out + (size_t)n * CDIM + c4) = o;
}

extern "C" void kernel_launch(void* const* d_in, const int* in_sizes, int n_in,
                              void* d_out, int out_size, void* d_ws, size_t ws_size,
                              hipStream_t stream) {
  const float* x  = (const float*)d_in[0];
  const float* wg = (const float*)d_in[1];
  const float* w1 = (const float*)d_in[2];
  const float* b1 = (const float*)d_in[3];
  const float* w2 = (const float*)d_in[4];
  const float* b2 = (const float*)d_in[5];
  float* out = (float*)d_out;

  char* ws = (char*)d_ws;
  int* cnt  = (int*)ws;
  int* fill = cnt + 8;
  int* offs = cnt + 16;
  size_t off = 256;
  int*   tok_e    = (int*)(ws + off);   off += (size_t)NTOK * 2 * 4;
  float* tok_w    = (float*)(ws + off); off += (size_t)NTOK * 2 * 4;
  int*   slot_tok = (int*)(ws + off);   off += (size_t)NTOK * 2 * 4;
  int*   tok_slot = (int*)(ws + off);   off += (size_t)NTOK * 2 * 4;
  u16*   xg  = (u16*)(ws + off); off += (size_t)NTOK * 2 * CDIM * 2;
  u16*   h   = (u16*)(ws + off); off += (size_t)NTOK * 2 * HDIM * 2;
  u16*   y   = (u16*)(ws + off); off += (size_t)NTOK * 2 * CDIM * 2;
  u16*   w1t = (u16*)(ws + off); off += (size_t)ENUM * CDIM * HDIM * 2;
  u16*   w2t = (u16*)(ws + off); off += (size_t)ENUM * HDIM * CDIM * 2;

  hipMemsetAsync(cnt, 0, 64, stream);

  wconv_kernel<<<dim3(HDIM / 64, CDIM / 64, ENUM), 256, 0, stream>>>(w1, w1t, CDIM, HDIM);
  wconv_kernel<<<dim3(CDIM / 64, HDIM / 64, ENUM), 256, 0, stream>>>(w2, w2t, HDIM, CDIM);

  gate_kernel<<<NTOK / 4, 256, 0, stream>>>(x, wg, cnt, tok_e, tok_w);
  offsets_kernel<<<1, 64, 0, stream>>>(cnt, offs);
  assign_kernel<<<NTOK / 256, 256, 0, stream>>>(tok_e, offs, fill, slot_tok, tok_slot);
  gather_kernel<<<NTOK * 2, 256, 0, stream>>>(x, slot_tok, xg);

  moe_gemm<1><<<dim3(HDIM / 128, NTOK / 128, ENUM), 256, 0, stream>>>(
      xg, w1t, b1, h, cnt, offs, CDIM, HDIM);
  moe_gemm<2><<<dim3(CDIM / 128, NTOK / 128, ENUM), 256, 0, stream>>>(
      h, w2t, b2, y, cnt, offs, HDIM, CDIM);

  combine_kernel<<<NTOK, 256, 0, stream>>>(y, tok_slot, tok_w, out);
}

// Round 10
// 541.677 us; speedup vs baseline: 1.5356x; 1.3987x over previous
//
#include <hip/hip_runtime.h>

#define NTOK 8192
#define CDIM 1024
#define ENUM 8
#define HDIM 4096

typedef unsigned short u16;
typedef unsigned int u32;
typedef __attribute__((ext_vector_type(8))) short s16x8;
typedef __attribute__((ext_vector_type(4))) float f32x4;
typedef __attribute__((ext_vector_type(4))) u32 u32x4;
typedef __attribute__((ext_vector_type(2))) u32 u32x2;

static __device__ __forceinline__ u16 f2bf(float f) {
  union { float f; u32 u; } v; v.f = f;
  u32 r = v.u + 0x7fffu + ((v.u >> 16) & 1u);
  return (u16)(r >> 16);
}
static __device__ __forceinline__ u32 pack2(float a, float b) {
  return (u32)f2bf(a) | ((u32)f2bf(b) << 16);
}
static __device__ __forceinline__ float bflo(u32 v) {
  union { u32 u; float f; } x; x.u = v << 16; return x.f;
}
static __device__ __forceinline__ float bfhi(u32 v) {
  union { u32 u; float f; } x; x.u = v & 0xffff0000u; return x.f;
}

typedef __attribute__((address_space(1))) const void gvoid;
typedef __attribute__((address_space(3))) void lvoid;
static __device__ __forceinline__ void gload16(const u16* g, u16* l) {
  __builtin_amdgcn_global_load_lds((gvoid*)g, (lvoid*)l, 16, 0, 0);
}

static __device__ __forceinline__ float gelu_fast(float v) {
  float u = v * (1.5957691216f + 0.1426929792f * v * v);
  return v / (1.f + __expf(-u));
}

// ---------------- weight convert + transpose: w[E][K][N] f32 -> wt[E][N][K] bf16 ----
__global__ void wconv_kernel(const float* __restrict__ w, u16* __restrict__ wt,
                             int K, int N) {
  __shared__ float lt[64][65];
  const int e = blockIdx.z, k0 = blockIdx.y * 64, n0 = blockIdx.x * 64;
  const float* src = w + (size_t)e * K * N;
  u16* dst = wt + (size_t)e * N * K;
  const int t = threadIdx.x;
  const int tr = t >> 4, tc = (t & 15) * 4;
#pragma unroll
  for (int i = 0; i < 4; ++i) {
    f32x4 v = __builtin_nontemporal_load(
        (const f32x4*)(src + (size_t)(k0 + tr + i * 16) * N + n0 + tc));
    lt[tr + i * 16][tc] = v.x; lt[tr + i * 16][tc + 1] = v.y;
    lt[tr + i * 16][tc + 2] = v.z; lt[tr + i * 16][tc + 3] = v.w;
  }
  __syncthreads();
#pragma unroll
  for (int i = 0; i < 4; ++i) {
    int n = tr + i * 16;
    uint2 o;
    o.x = pack2(lt[tc + 0][n], lt[tc + 1][n]);
    o.y = pack2(lt[tc + 2][n], lt[tc + 3][n]);
    *(uint2*)(dst + (size_t)(n0 + n) * K + k0 + tc) = o;
  }
}

// ---------------- gating: 32 tokens/block, LDS-aggregated counts ----------------
__global__ void gate_kernel(const float* __restrict__ x, const float* __restrict__ wg,
                            int* __restrict__ cnt, int* __restrict__ tok_e,
                            float* __restrict__ tok_w) {
  __shared__ int lcnt[ENUM];
  const int tid = threadIdx.x;
  if (tid < ENUM) lcnt[tid] = 0;
  __syncthreads();
  const int wv = tid >> 6, lane = tid & 63;
  const int tbase = blockIdx.x * 32 + wv * 8;
  for (int t = 0; t < 8; ++t) {
    const int gw = tbase + t;
    const float* xr = x + (size_t)gw * CDIM;
    float acc[ENUM];
#pragma unroll
    for (int e = 0; e < ENUM; ++e) acc[e] = 0.f;
#pragma unroll 4
    for (int i = 0; i < CDIM / 64; ++i) {
      int c = i * 64 + lane;
      float xv = xr[c];
      float4 wa = *(const float4*)(wg + (size_t)c * ENUM);
      float4 wb = *(const float4*)(wg + (size_t)c * ENUM + 4);
      acc[0] += xv * wa.x; acc[1] += xv * wa.y; acc[2] += xv * wa.z; acc[3] += xv * wa.w;
      acc[4] += xv * wb.x; acc[5] += xv * wb.y; acc[6] += xv * wb.z; acc[7] += xv * wb.w;
    }
#pragma unroll
    for (int e = 0; e < ENUM; ++e) {
#pragma unroll
      for (int off = 32; off > 0; off >>= 1) acc[e] += __shfl_xor(acc[e], off);
    }
    if (lane == 0) {
      int i0 = 0; float v0 = acc[0];
#pragma unroll
      for (int e = 1; e < ENUM; ++e) if (acc[e] > v0) { v0 = acc[e]; i0 = e; }
      int i1 = -1; float v1 = -3.4e38f;
#pragma unroll
      for (int e = 0; e < ENUM; ++e) if (e != i0 && acc[e] > v1) { v1 = acc[e]; i1 = e; }
      float ex = expf(v1 - v0);
      float den = 1.f + ex;
      tok_e[gw * 2] = i0;     tok_w[gw * 2] = 1.f / den;
      tok_e[gw * 2 + 1] = i1; tok_w[gw * 2 + 1] = ex / den;
      atomicAdd(&lcnt[i0], 1); atomicAdd(&lcnt[i1], 1);
    }
  }
  __syncthreads();
  if (tid < ENUM) {
    int v = lcnt[tid];
    if (v) atomicAdd(&cnt[tid], v);
  }
}

__global__ void offsets_kernel(const int* __restrict__ cnt, int* __restrict__ offs) {
  if (threadIdx.x == 0 && blockIdx.x == 0) {
    int s = 0;
    for (int e = 0; e < ENUM; ++e) { offs[e] = s; s += cnt[e]; }
  }
}

// ---------------- assign: LDS-aggregated ranks, 8 global atomics/block ----------
__global__ void assign_kernel(const int* __restrict__ tok_e, const int* __restrict__ offs,
                              int* __restrict__ fill, int* __restrict__ slot_tok,
                              int* __restrict__ tok_slot) {
  __shared__ int lfill[ENUM], lbase[ENUM];
  const int tid = threadIdx.x;
  if (tid < ENUM) lfill[tid] = 0;
  __syncthreads();
  const int n = blockIdx.x * 256 + tid;
  const int e0 = tok_e[n * 2], e1 = tok_e[n * 2 + 1];
  const int p0 = atomicAdd(&lfill[e0], 1);
  const int p1 = atomicAdd(&lfill[e1], 1);
  __syncthreads();
  if (tid < ENUM) lbase[tid] = lfill[tid] ? atomicAdd(&fill[tid], lfill[tid]) : 0;
  __syncthreads();
  const int s0 = offs[e0] + lbase[e0] + p0;
  const int s1 = offs[e1] + lbase[e1] + p1;
  slot_tok[s0] = n; tok_slot[n * 2] = s0;
  slot_tok[s1] = n; tok_slot[n * 2 + 1] = s1;
}

__global__ void gather_kernel(const float* __restrict__ x, const int* __restrict__ slot_tok,
                              u16* __restrict__ xg) {
  int gid = blockIdx.x * blockDim.x + threadIdx.x;
  int slot = gid >> 8;
  int c4 = (gid & 255) * 4;
  int tok = slot_tok[slot];
  float4 v = *(const float4*)(x + (size_t)tok * CDIM + c4);
  uint2 o; o.x = pack2(v.x, v.y); o.y = pack2(v.z, v.w);
  *(uint2*)(xg + (size_t)slot * CDIM + c4) = o;
}

// ---------------- expert GEMMs: 256x256, BK=64 (2 k-halves of 32), fine-phase ----
// 8 waves (2M x 4N), per-wave 128x64 out. LDS [2 dbuf][Ak0,Bk0,Ak1,Bk1] 16KB each.
// Per phase: {ds_read frags, stage 1 half (2 gload_lds), BAR, lgkmcnt(0)+SB,
//            setprio(1), 16 MFMA, setprio(0), vmcnt(4)+SB, BAR}.
// 64B LDS rows: bank-quad = 4*(row&1)+oct -> swizzle key (row>>1)&3 on BOTH sides
// (source k-octet and ds_read octet). Tail tile peeled with vmcnt(2)/vmcnt(0).
// XCD-chunk: per-expert r<8*NTI: XCD k=r%8 owns mt=(k+e)%8, nt=r/8; rest linear.
template <int PHASE, int KK, int NN, int NTI>
__global__ __launch_bounds__(512, 2) void moe_gemm(
    const u16* __restrict__ Ag, const u16* __restrict__ Bt, const float* __restrict__ bias,
    u16* __restrict__ outp,
    const int* __restrict__ cnts, const int* __restrict__ offs) {
  const int per_e = 64 * NTI;
  const int e = blockIdx.x / per_e;
  const int r = blockIdx.x % per_e;
  int mt, nt;
  if (r < 8 * NTI) {
    mt = ((r & 7) + e) & 7;
    nt = r >> 3;
  } else {
    const int rr = r - 8 * NTI;
    mt = 8 + rr / NTI;
    nt = rr % NTI;
  }
  const int cnt = cnts[e];
  if (mt * 256 >= cnt) return;
  const int moff = offs[e];

  const int tid = threadIdx.x;
  const int wv = tid >> 6, ln = tid & 63;
  const int lr = ln & 15, lg = ln >> 4;
  const int wm = wv >> 2, wn = wv & 3;

  __shared__ __align__(16) u16 lds[2][4][8192];  // 128 KB

  const u16* Abase = Ag + (size_t)moff * KK;
  const u16* Bbase = Bt + (size_t)e * NN * KK + (size_t)nt * 256 * KK;

  // staging: row = tid>>2 (64B rows), dest oct = tid&3, src oct ^= (row>>1)&3
  const int srow = tid >> 2;
  const int slo = (tid & 3) ^ ((srow >> 1) & 3);
  int ra0 = mt * 256 + srow;       ra0 = ra0 < cnt ? ra0 : cnt - 1;
  int ra1 = mt * 256 + srow + 128; ra1 = ra1 < cnt ? ra1 : cnt - 1;
  const size_t aoff0 = (size_t)ra0 * KK + slo * 8;
  const size_t aoff1 = (size_t)ra1 * KK + slo * 8;
  const size_t boff0 = (size_t)srow * KK + slo * 8;
  const size_t boff1 = (size_t)(srow + 128) * KK + slo * 8;
  const int dst0 = wv * 512;   // u16; wave-uniform (HW adds lane*16B)
  const int dst1 = wv * 512 + 4096;

  // frag read: physical oct = lg ^ ((row>>1)&3); row bits 1,2 come from lr
  const int fsw = (lg ^ ((lr >> 1) & 3)) * 8;

  f32x4 acc[8][4];
#pragma unroll
  for (int m = 0; m < 8; ++m)
#pragma unroll
    for (int n = 0; n < 4; ++n) {
      acc[m][n][0] = 0.f; acc[m][n][1] = 0.f; acc[m][n][2] = 0.f; acc[m][n][3] = 0.f;
    }

  s16x8 fa[8], fb[2];
  auto RDFA = [&](const u16* buf) {
#pragma unroll
    for (int m = 0; m < 8; ++m)
      fa[m] = *(const s16x8*)(buf + (wm * 128 + m * 16 + lr) * 32 + fsw);
  };
  auto RDFB = [&](const u16* buf, int ng) {
#pragma unroll
    for (int n = 0; n < 2; ++n)
      fb[n] = *(const s16x8*)(buf + (wn * 64 + (ng * 2 + n) * 16 + lr) * 32 + fsw);
  };
  auto MF = [&](int ng) {
#pragma unroll
    for (int m = 0; m < 8; ++m)
#pragma unroll
      for (int n = 0; n < 2; ++n)
        acc[m][ng * 2 + n] =
            __builtin_amdgcn_mfma_f32_16x16x32_bf16(fa[m], fb[n], acc[m][ng * 2 + n], 0, 0, 0);
  };

#define BAR() __builtin_amdgcn_s_barrier()
#define SB() __builtin_amdgcn_sched_barrier(0)
#define WAITL0() asm volatile("s_waitcnt lgkmcnt(0)" ::: "memory")
#define WV(N) asm volatile("s_waitcnt vmcnt(" #N ")" ::: "memory")

  const int nk = KK / 64;

  // prologue: stage tile0 (Ak0,Bk0,Ak1,Bk1)
  gload16(Abase + aoff0, &lds[0][0][0] + dst0);
  gload16(Abase + aoff1, &lds[0][0][0] + dst1);
  gload16(Bbase + boff0, &lds[0][1][0] + dst0);
  gload16(Bbase + boff1, &lds[0][1][0] + dst1);
  gload16(Abase + aoff0 + 32, &lds[0][2][0] + dst0);
  gload16(Abase + aoff1 + 32, &lds[0][2][0] + dst1);
  gload16(Bbase + boff0 + 32, &lds[0][3][0] + dst0);
  gload16(Bbase + boff1 + 32, &lds[0][3][0] + dst1);
  WV(4); SB(); BAR();  // Ak0,Bk0 landed

  for (int t = 0; t < nk - 1; ++t) {
    const int d = t & 1, nd = d ^ 1;
    const u16* A0 = &lds[d][0][0];
    const u16* B0 = &lds[d][1][0];
    const u16* A1 = &lds[d][2][0];
    const u16* B1 = &lds[d][3][0];
    const size_t kadd = (size_t)(t + 1) * 64;

    // phase 0: ks0 n{0,1}; stage Ak0(t+1)
    RDFA(A0); RDFB(B0, 0);
    gload16(Abase + aoff0 + kadd, &lds[nd][0][0] + dst0);
    gload16(Abase + aoff1 + kadd, &lds[nd][0][0] + dst1);
    SB(); BAR(); WAITL0(); SB();
    __builtin_amdgcn_s_setprio(1); MF(0); __builtin_amdgcn_s_setprio(0);
    WV(4); SB(); BAR();
    // phase 1: ks0 n{2,3}; stage Bk0(t+1)
    RDFB(B0, 1);
    gload16(Bbase + boff0 + kadd, &lds[nd][1][0] + dst0);
    gload16(Bbase + boff1 + kadd, &lds[nd][1][0] + dst1);
    SB(); BAR(); WAITL0(); SB();
    __builtin_amdgcn_s_setprio(1); MF(1); __builtin_amdgcn_s_setprio(0);
    WV(4); SB(); BAR();
    // phase 2: ks1 n{0,1}; stage Ak1(t+1)
    RDFA(A1); RDFB(B1, 0);
    gload16(Abase + aoff0 + kadd + 32, &lds[nd][2][0] + dst0);
    gload16(Abase + aoff1 + kadd + 32, &lds[nd][2][0] + dst1);
    SB(); BAR(); WAITL0(); SB();
    __builtin_amdgcn_s_setprio(1); MF(0); __builtin_amdgcn_s_setprio(0);
    WV(4); SB(); BAR();
    // phase 3: ks1 n{2,3}; stage Bk1(t+1)
    RDFB(B1, 1);
    gload16(Bbase + boff0 + kadd + 32, &lds[nd][3][0] + dst0);
    gload16(Bbase + boff1 + kadd + 32, &lds[nd][3][0] + dst1);
    SB(); BAR(); WAITL0(); SB();
    __builtin_amdgcn_s_setprio(1); MF(1); __builtin_amdgcn_s_setprio(0);
    WV(4); SB(); BAR();
  }

  // tail tile t = nk-1 (no staging; drain Ak1/Bk1 with vmcnt 2 then 0)
  {
    const int d = (nk - 1) & 1;
    const u16* A0 = &lds[d][0][0];
    const u16* B0 = &lds[d][1][0];
    const u16* A1 = &lds[d][2][0];
    const u16* B1 = &lds[d][3][0];
    RDFA(A0); RDFB(B0, 0);
    SB(); BAR(); WAITL0(); SB();
    __builtin_amdgcn_s_setprio(1); MF(0); __builtin_amdgcn_s_setprio(0);
    WV(2); SB(); BAR();
    RDFB(B0, 1);
    SB(); BAR(); WAITL0(); SB();
    __builtin_amdgcn_s_setprio(1); MF(1); __builtin_amdgcn_s_setprio(0);
    WV(0); SB(); BAR();
    RDFA(A1); RDFB(B1, 0);
    SB(); BAR(); WAITL0(); SB();
    __builtin_amdgcn_s_setprio(1); MF(0); __builtin_amdgcn_s_setprio(0);
    SB(); BAR();
    RDFB(B1, 1);
    SB(); BAR(); WAITL0(); SB();
    __builtin_amdgcn_s_setprio(1); MF(1); __builtin_amdgcn_s_setprio(0);
  }

  asm volatile("s_waitcnt vmcnt(0) lgkmcnt(0)" ::: "memory");
  SB();
  __syncthreads();

  // epilogue: bias (+gelu), repack bf16 via full-LDS tile, coalesced stores
  u16* lT = &lds[0][0][0];
  float bv[4];
#pragma unroll
  for (int n = 0; n < 4; ++n)
    bv[n] = bias[(size_t)e * NN + nt * 256 + wn * 64 + n * 16 + lr];
#pragma unroll
  for (int m = 0; m < 8; ++m) {
#pragma unroll
    for (int r4 = 0; r4 < 4; ++r4) {
      int row = wm * 128 + m * 16 + lg * 4 + r4;
#pragma unroll
      for (int n = 0; n < 4; ++n) {
        int col = wn * 64 + n * 16 + lr;
        float v = acc[m][n][r4] + bv[n];
        if (PHASE == 1) v = gelu_fast(v);
        lT[row * 256 + col] = f2bf(v);
      }
    }
  }
  __syncthreads();
#pragma unroll
  for (int j = 0; j < 16; ++j) {
    int idx = j * 512 + tid;
    int row = idx >> 5;
    int cu = idx & 31;
    int grow = mt * 256 + row;
    if (grow < cnt) {
      u32x4 v = ((const u32x4*)lT)[idx];
      *(u32x4*)(outp + (size_t)(moff + grow) * NN + nt * 256 + cu * 8) = v;
    }
  }
#undef BAR
#undef SB
#undef WAITL0
#undef WV
}

// out[tok] = w0 * y[slot0] + w1 * y[slot1]
__global__ void combine_kernel(const u16* __restrict__ y, const int* __restrict__ tok_slot,
                               const float* __restrict__ tok_w, float* __restrict__ out) {
  int gid = blockIdx.x * blockDim.x + threadIdx.x;
  int n = gid >> 8;
  int c4 = (gid & 255) * 4;
  int s0 = tok_slot[n * 2], s1 = tok_slot[n * 2 + 1];
  float w0 = tok_w[n * 2], w1 = tok_w[n * 2 + 1];
  u32x2 a = __builtin_nontemporal_load((const u32x2*)(y + (size_t)s0 * CDIM + c4));
  u32x2 b = __builtin_nontemporal_load((const u32x2*)(y + (size_t)s1 * CDIM + c4));
  float4 o;
  o.x = w0 * bflo(a.x) + w1 * bflo(b.x);
  o.y = w0 * bfhi(a.x) + w1 * bfhi(b.x);
  o.z = w0 * bflo(a.y) + w1 * bflo(b.y);
  o.w = w0 * bfhi(a.y) + w1 * bfhi(b.y);
  *(float4*)(out + (size_t)n * CDIM + c4) = o;
}

extern "C" void kernel_launch(void* const* d_in, const int* in_sizes, int n_in,
                              void* d_out, int out_size, void* d_ws, size_t ws_size,
                              hipStream_t stream) {
  const float* x  = (const float*)d_in[0];
  const float* wg = (const float*)d_in[1];
  const float* w1 = (const float*)d_in[2];
  const float* b1 = (const float*)d_in[3];
  const float* w2 = (const float*)d_in[4];
  const float* b2 = (const float*)d_in[5];
  float* out = (float*)d_out;

  char* ws = (char*)d_ws;
  int* cnt  = (int*)ws;
  int* fill = cnt + 8;
  int* offs = cnt + 16;
  size_t off = 256;
  int*   tok_e    = (int*)(ws + off);   off += (size_t)NTOK * 2 * 4;
  float* tok_w    = (float*)(ws + off); off += (size_t)NTOK * 2 * 4;
  int*   slot_tok = (int*)(ws + off);   off += (size_t)NTOK * 2 * 4;
  int*   tok_slot = (int*)(ws + off);   off += (size_t)NTOK * 2 * 4;
  u16*   xg  = (u16*)(ws + off); off += (size_t)NTOK * 2 * CDIM * 2;
  u16*   h   = (u16*)(ws + off); off += (size_t)NTOK * 2 * HDIM * 2;
  u16*   y   = (u16*)(ws + off); off += (size_t)NTOK * 2 * CDIM * 2;
  u16*   w1t = (u16*)(ws + off); off += (size_t)ENUM * CDIM * HDIM * 2;
  u16*   w2t = (u16*)(ws + off); off += (size_t)ENUM * HDIM * CDIM * 2;

  hipMemsetAsync(cnt, 0, 64, stream);

  wconv_kernel<<<dim3(HDIM / 64, CDIM / 64, ENUM), 256, 0, stream>>>(w1, w1t, CDIM, HDIM);
  wconv_kernel<<<dim3(CDIM / 64, HDIM / 64, ENUM), 256, 0, stream>>>(w2, w2t, HDIM, CDIM);

  gate_kernel<<<NTOK / 32, 256, 0, stream>>>(x, wg, cnt, tok_e, tok_w);
  offsets_kernel<<<1, 64, 0, stream>>>(cnt, offs);
  assign_kernel<<<NTOK / 256, 256, 0, stream>>>(tok_e, offs, fill, slot_tok, tok_slot);
  gather_kernel<<<NTOK * 2, 256, 0, stream>>>(x, slot_tok, xg);

  moe_gemm<1, CDIM, HDIM, 16><<<ENUM * 64 * 16, 512, 0, stream>>>(
      xg, w1t, b1, h, cnt, offs);
  moe_gemm<2, HDIM, CDIM, 4><<<ENUM * 64 * 4, 512, 0, stream>>>(
      h, w2t, b2, y, cnt, offs);

  combine_kernel<<<NTOK, 256, 0, stream>>>(y, tok_slot, tok_w, out);
}

// Round 11
// 507.505 us; speedup vs baseline: 1.6390x; 1.0673x over previous
//
#include <hip/hip_runtime.h>

#define NTOK 8192
#define CDIM 1024
#define ENUM 8
#define HDIM 4096

typedef unsigned short u16;
typedef unsigned int u32;
typedef __attribute__((ext_vector_type(8))) short s16x8;
typedef __attribute__((ext_vector_type(4))) float f32x4;
typedef __attribute__((ext_vector_type(4))) u32 u32x4;
typedef __attribute__((ext_vector_type(2))) u32 u32x2;

static __device__ __forceinline__ u16 f2bf(float f) {
  union { float f; u32 u; } v; v.f = f;
  u32 r = v.u + 0x7fffu + ((v.u >> 16) & 1u);
  return (u16)(r >> 16);
}
static __device__ __forceinline__ u32 pack2(float a, float b) {
  return (u32)f2bf(a) | ((u32)f2bf(b) << 16);
}
static __device__ __forceinline__ float bflo(u32 v) {
  union { u32 u; float f; } x; x.u = v << 16; return x.f;
}
static __device__ __forceinline__ float bfhi(u32 v) {
  union { u32 u; float f; } x; x.u = v & 0xffff0000u; return x.f;
}

typedef __attribute__((address_space(1))) const void gvoid;
typedef __attribute__((address_space(3))) void lvoid;
static __device__ __forceinline__ void gload16(const u16* g, u16* l) {
  __builtin_amdgcn_global_load_lds((gvoid*)g, (lvoid*)l, 16, 0, 0);
}

static __device__ __forceinline__ float gelu_fast(float v) {
  float u = v * (1.5957691216f + 0.1426929792f * v * v);
  return v / (1.f + __expf(-u));
}

// ---------------- weight convert + transpose: w[E][K][N] f32 -> wt[E][N][K] bf16 ----
__global__ void wconv_kernel(const float* __restrict__ w, u16* __restrict__ wt,
                             int K, int N) {
  __shared__ float lt[64][65];
  const int e = blockIdx.z, k0 = blockIdx.y * 64, n0 = blockIdx.x * 64;
  const float* src = w + (size_t)e * K * N;
  u16* dst = wt + (size_t)e * N * K;
  const int t = threadIdx.x;
  const int tr = t >> 4, tc = (t & 15) * 4;
#pragma unroll
  for (int i = 0; i < 4; ++i) {
    f32x4 v = __builtin_nontemporal_load(
        (const f32x4*)(src + (size_t)(k0 + tr + i * 16) * N + n0 + tc));
    lt[tr + i * 16][tc] = v.x; lt[tr + i * 16][tc + 1] = v.y;
    lt[tr + i * 16][tc + 2] = v.z; lt[tr + i * 16][tc + 3] = v.w;
  }
  __syncthreads();
#pragma unroll
  for (int i = 0; i < 4; ++i) {
    int n = tr + i * 16;
    uint2 o;
    o.x = pack2(lt[tc + 0][n], lt[tc + 1][n]);
    o.y = pack2(lt[tc + 2][n], lt[tc + 3][n]);
    *(uint2*)(dst + (size_t)(n0 + n) * K + k0 + tc) = o;
  }
}

// ---------------- gating: 32 tokens/block, LDS-aggregated counts ----------------
__global__ void gate_kernel(const float* __restrict__ x, const float* __restrict__ wg,
                            int* __restrict__ cnt, int* __restrict__ tok_e,
                            float* __restrict__ tok_w) {
  __shared__ int lcnt[ENUM];
  const int tid = threadIdx.x;
  if (tid < ENUM) lcnt[tid] = 0;
  __syncthreads();
  const int wv = tid >> 6, lane = tid & 63;
  const int tbase = blockIdx.x * 32 + wv * 8;
  for (int t = 0; t < 8; ++t) {
    const int gw = tbase + t;
    const float* xr = x + (size_t)gw * CDIM;
    float acc[ENUM];
#pragma unroll
    for (int e = 0; e < ENUM; ++e) acc[e] = 0.f;
#pragma unroll 4
    for (int i = 0; i < CDIM / 64; ++i) {
      int c = i * 64 + lane;
      float xv = xr[c];
      float4 wa = *(const float4*)(wg + (size_t)c * ENUM);
      float4 wb = *(const float4*)(wg + (size_t)c * ENUM + 4);
      acc[0] += xv * wa.x; acc[1] += xv * wa.y; acc[2] += xv * wa.z; acc[3] += xv * wa.w;
      acc[4] += xv * wb.x; acc[5] += xv * wb.y; acc[6] += xv * wb.z; acc[7] += xv * wb.w;
    }
#pragma unroll
    for (int e = 0; e < ENUM; ++e) {
#pragma unroll
      for (int off = 32; off > 0; off >>= 1) acc[e] += __shfl_xor(acc[e], off);
    }
    if (lane == 0) {
      int i0 = 0; float v0 = acc[0];
#pragma unroll
      for (int e = 1; e < ENUM; ++e) if (acc[e] > v0) { v0 = acc[e]; i0 = e; }
      int i1 = -1; float v1 = -3.4e38f;
#pragma unroll
      for (int e = 0; e < ENUM; ++e) if (e != i0 && acc[e] > v1) { v1 = acc[e]; i1 = e; }
      float ex = expf(v1 - v0);
      float den = 1.f + ex;
      tok_e[gw * 2] = i0;     tok_w[gw * 2] = 1.f / den;
      tok_e[gw * 2 + 1] = i1; tok_w[gw * 2 + 1] = ex / den;
      atomicAdd(&lcnt[i0], 1); atomicAdd(&lcnt[i1], 1);
    }
  }
  __syncthreads();
  if (tid < ENUM) {
    int v = lcnt[tid];
    if (v) atomicAdd(&cnt[tid], v);
  }
}

__global__ void offsets_kernel(const int* __restrict__ cnt, int* __restrict__ offs) {
  if (threadIdx.x == 0 && blockIdx.x == 0) {
    int s = 0;
    for (int e = 0; e < ENUM; ++e) { offs[e] = s; s += cnt[e]; }
  }
}

// ---------------- assign: LDS-aggregated ranks, 8 global atomics/block ----------
__global__ void assign_kernel(const int* __restrict__ tok_e, const int* __restrict__ offs,
                              int* __restrict__ fill, int* __restrict__ slot_tok,
                              int* __restrict__ tok_slot) {
  __shared__ int lfill[ENUM], lbase[ENUM];
  const int tid = threadIdx.x;
  if (tid < ENUM) lfill[tid] = 0;
  __syncthreads();
  const int n = blockIdx.x * 256 + tid;
  const int e0 = tok_e[n * 2], e1 = tok_e[n * 2 + 1];
  const int p0 = atomicAdd(&lfill[e0], 1);
  const int p1 = atomicAdd(&lfill[e1], 1);
  __syncthreads();
  if (tid < ENUM) lbase[tid] = lfill[tid] ? atomicAdd(&fill[tid], lfill[tid]) : 0;
  __syncthreads();
  const int s0 = offs[e0] + lbase[e0] + p0;
  const int s1 = offs[e1] + lbase[e1] + p1;
  slot_tok[s0] = n; tok_slot[n * 2] = s0;
  slot_tok[s1] = n; tok_slot[n * 2 + 1] = s1;
}

__global__ void gather_kernel(const float* __restrict__ x, const int* __restrict__ slot_tok,
                              u16* __restrict__ xg) {
  int gid = blockIdx.x * blockDim.x + threadIdx.x;
  int slot = gid >> 8;
  int c4 = (gid & 255) * 4;
  int tok = slot_tok[slot];
  float4 v = *(const float4*)(x + (size_t)tok * CDIM + c4);
  uint2 o; o.x = pack2(v.x, v.y); o.y = pack2(v.z, v.w);
  *(uint2*)(xg + (size_t)slot * CDIM + c4) = o;
}

// ---------------- expert GEMMs (R9-proven 128x128, BK=64, 4 waves, XCD-chunked) ----
template <int PHASE>
__global__ __launch_bounds__(256, 2) void moe_gemm(
    const u16* __restrict__ Ag, const u16* __restrict__ Bt, const float* __restrict__ bias,
    u16* __restrict__ outp,
    const int* __restrict__ cnts, const int* __restrict__ offs,
    int K, int Nn) {
  const int e = blockIdx.z;
  const int cnt = cnts[e];
  const int NT = gridDim.x;
  const int MTC = gridDim.y >> 3;               // 8
  const int r = blockIdx.y * NT + blockIdx.x;   // launch-order flat (x fastest)
  const int k = r & 7;                          // XCD id
  const int i = r >> 3;                         // inner
  const int ck = (k + e) & 7;                   // rotated chunk for balance
  const int mt = ck * MTC + (i % MTC);
  const int nt = i / MTC;
  if (mt * 128 >= cnt) return;
  const int moff = offs[e];
  const int tid = threadIdx.x;
  const int wv = tid >> 6, ln = tid & 63;
  const int lr = ln & 15, lg = ln >> 4;
  const int wm = wv >> 1, wn = wv & 1;

  __shared__ __align__(16) u16 lds[2][128 * 64];
  u16* lA = lds[0];
  u16* lB = lds[1];

  const u16* Abase = Ag + (size_t)moff * K;
  const u16* Bbase = Bt + (size_t)e * Nn * K + (size_t)nt * 128 * K;

  const int srow = ln >> 3;                       // row-in-chunk 0..7
  const int sk = (((ln & 7) ^ srow)) * 8;         // swizzled source octet offset

  f32x4 acc[4][4];
#pragma unroll
  for (int m = 0; m < 4; ++m)
#pragma unroll
    for (int n = 0; n < 4; ++n) {
      acc[m][n][0] = 0.f; acc[m][n][1] = 0.f; acc[m][n][2] = 0.f; acc[m][n][3] = 0.f;
    }

  const int nk = K / 64;
  for (int kt = 0; kt < nk; ++kt) {
#pragma unroll
    for (int i4 = 0; i4 < 4; ++i4) {
      int c = wv * 4 + i4;
      int ra = mt * 128 + c * 8 + srow;
      ra = ra < cnt ? ra : cnt - 1;  // clamp: padded rows discarded in epilogue
      gload16(Abase + (size_t)ra * K + kt * 64 + sk, lA + c * 512);
      gload16(Bbase + (size_t)(c * 8 + srow) * K + kt * 64 + sk, lB + c * 512);
    }
    __syncthreads();
#pragma unroll
    for (int ko = 0; ko < 2; ++ko) {
      s16x8 af[4], bfr[4];
      const int lsw = lr & 7;
#pragma unroll
      for (int m = 0; m < 4; ++m)
        af[m] = *(const s16x8*)(lA + (wm * 64 + m * 16 + lr) * 64 + ((ko * 4 + lg) ^ lsw) * 8);
#pragma unroll
      for (int n = 0; n < 4; ++n)
        bfr[n] = *(const s16x8*)(lB + (wn * 64 + n * 16 + lr) * 64 + ((ko * 4 + lg) ^ lsw) * 8);
#pragma unroll
      for (int m = 0; m < 4; ++m)
#pragma unroll
        for (int n = 0; n < 4; ++n)
          acc[m][n] = __builtin_amdgcn_mfma_f32_16x16x32_bf16(af[m], bfr[n], acc[m][n], 0, 0, 0);
    }
    __syncthreads();
  }

  // epilogue: bias (+gelu), pack bf16 into LDS tile [128][128], coalesced store
  u16* lT = lds[0];
  float bv[4];
#pragma unroll
  for (int n = 0; n < 4; ++n) bv[n] = bias[(size_t)e * Nn + nt * 128 + wn * 64 + n * 16 + lr];
#pragma unroll
  for (int m = 0; m < 4; ++m) {
#pragma unroll
    for (int r4 = 0; r4 < 4; ++r4) {
      int row = wm * 64 + m * 16 + lg * 4 + r4;
#pragma unroll
      for (int n = 0; n < 4; ++n) {
        int col = wn * 64 + n * 16 + lr;
        float v = acc[m][n][r4] + bv[n];
        if (PHASE == 1) v = gelu_fast(v);
        lT[row * 128 + col] = f2bf(v);
      }
    }
  }
  __syncthreads();
#pragma unroll
  for (int j = 0; j < 8; ++j) {
    int u = j * 256 + tid;           // u32x4 index into 128x128 tile
    int row = u >> 4;                // 16 u32x4 per row
    int colb = (u & 15) * 8;
    int grow = mt * 128 + row;
    if (grow < cnt) {
      u32x4 v = ((const u32x4*)lT)[u];
      *(u32x4*)(outp + (size_t)(moff + grow) * Nn + nt * 128 + colb) = v;
    }
  }
}

// out[tok] = w0 * y[slot0] + w1 * y[slot1]   (y read-once -> NT loads)
__global__ void combine_kernel(const u16* __restrict__ y, const int* __restrict__ tok_slot,
                               const float* __restrict__ tok_w, float* __restrict__ out) {
  int gid = blockIdx.x * blockDim.x + threadIdx.x;
  int n = gid >> 8;
  int c4 = (gid & 255) * 4;
  int s0 = tok_slot[n * 2], s1 = tok_slot[n * 2 + 1];
  float w0 = tok_w[n * 2], w1 = tok_w[n * 2 + 1];
  u32x2 a = __builtin_nontemporal_load((const u32x2*)(y + (size_t)s0 * CDIM + c4));
  u32x2 b = __builtin_nontemporal_load((const u32x2*)(y + (size_t)s1 * CDIM + c4));
  float4 o;
  o.x = w0 * bflo(a.x) + w1 * bflo(b.x);
  o.y = w0 * bfhi(a.x) + w1 * bfhi(b.x);
  o.z = w0 * bflo(a.y) + w1 * bflo(b.y);
  o.w = w0 * bfhi(a.y) + w1 * bfhi(b.y);
  *(float4*)(out + (size_t)n * CDIM + c4) = o;
}

extern "C" void kernel_launch(void* const* d_in, const int* in_sizes, int n_in,
                              void* d_out, int out_size, void* d_ws, size_t ws_size,
                              hipStream_t stream) {
  const float* x  = (const float*)d_in[0];
  const float* wg = (const float*)d_in[1];
  const float* w1 = (const float*)d_in[2];
  const float* b1 = (const float*)d_in[3];
  const float* w2 = (const float*)d_in[4];
  const float* b2 = (const float*)d_in[5];
  float* out = (float*)d_out;

  char* ws = (char*)d_ws;
  int* cnt  = (int*)ws;
  int* fill = cnt + 8;
  int* offs = cnt + 16;
  size_t off = 256;
  int*   tok_e    = (int*)(ws + off);   off += (size_t)NTOK * 2 * 4;
  float* tok_w    = (float*)(ws + off); off += (size_t)NTOK * 2 * 4;
  int*   slot_tok = (int*)(ws + off);   off += (size_t)NTOK * 2 * 4;
  int*   tok_slot = (int*)(ws + off);   off += (size_t)NTOK * 2 * 4;
  u16*   xg  = (u16*)(ws + off); off += (size_t)NTOK * 2 * CDIM * 2;
  u16*   h   = (u16*)(ws + off); off += (size_t)NTOK * 2 * HDIM * 2;
  u16*   y   = (u16*)(ws + off); off += (size_t)NTOK * 2 * CDIM * 2;
  u16*   w1t = (u16*)(ws + off); off += (size_t)ENUM * CDIM * HDIM * 2;
  u16*   w2t = (u16*)(ws + off); off += (size_t)ENUM * HDIM * CDIM * 2;

  hipMemsetAsync(cnt, 0, 64, stream);

  wconv_kernel<<<dim3(HDIM / 64, CDIM / 64, ENUM), 256, 0, stream>>>(w1, w1t, CDIM, HDIM);
  wconv_kernel<<<dim3(CDIM / 64, HDIM / 64, ENUM), 256, 0, stream>>>(w2, w2t, HDIM, CDIM);

  gate_kernel<<<NTOK / 32, 256, 0, stream>>>(x, wg, cnt, tok_e, tok_w);
  offsets_kernel<<<1, 64, 0, stream>>>(cnt, offs);
  assign_kernel<<<NTOK / 256, 256, 0, stream>>>(tok_e, offs, fill, slot_tok, tok_slot);
  gather_kernel<<<NTOK * 2, 256, 0, stream>>>(x, slot_tok, xg);

  moe_gemm<1><<<dim3(HDIM / 128, NTOK / 128, ENUM), 256, 0, stream>>>(
      xg, w1t, b1, h, cnt, offs, CDIM, HDIM);
  moe_gemm<2><<<dim3(CDIM / 128, NTOK / 128, ENUM), 256, 0, stream>>>(
      h, w2t, b2, y, cnt, offs, HDIM, CDIM);

  combine_kernel<<<NTOK, 256, 0, stream>>>(y, tok_slot, tok_w, out);
}